// Round 6
// baseline (750.660 us; speedup 1.0000x reference)
//
#include <hip/hip_runtime.h>
#include <hip/hip_bf16.h>

#define S_LEN  1024
#define BATCH  16
#define IDIM   1024
#define DDIM   1024
#define NG     4096     // 4*DDIM
#define BD     16384    // BATCH*DDIM
#define LAYERS 2
#define PF     16       // pre pad steps per chain (covers all prefetch over-read)
#define PFP    8        // parallel-pass prefetch depth (uint4 units)
#define NSEG   32       // time segments for the parallel scan

typedef __attribute__((ext_vector_type(8))) short   short8;
typedef __attribute__((ext_vector_type(4))) float   floatx4;
typedef __attribute__((address_space(1))) void      as1_void;
typedef __attribute__((address_space(3))) void      as3_void;

#define L2E  1.4426950408889634f   // log2(e)
#define LN2  0.6931471805599453f

#define EXP2F(x) exp2f(x)

// RNE f32->bf16, 3 ops (NaN irrelevant here)
static __device__ __forceinline__ unsigned short f2bf(float x) {
    unsigned int u = __float_as_uint(x);
    return (unsigned short)((u + 0x7fffu + ((u >> 16) & 1u)) >> 16);
}

// ---------------------------------------------------------------------------
// Dtype detect: read W0 head AS bf16; f32 garbage -> max |v| huge.
// flag: 1 = f32 I/O, 0 = bf16 I/O.
// ---------------------------------------------------------------------------
__global__ void detect_dtype(const void* w, int* flag)
{
    const __hip_bfloat16* p = (const __hip_bfloat16*)w;
    float mx = 0.0f;
    for (int i = threadIdx.x; i < 4096; i += 64) {
        float v = __bfloat162float(p[i]);
        float a = fabsf(v);
        if (!(a == a)) a = 1e30f;
        mx = fmaxf(mx, a);
    }
#pragma unroll
    for (int o = 32; o > 0; o >>= 1)
        mx = fmaxf(mx, __shfl_down(mx, o, 64));
    if (threadIdx.x == 0) *flag = (mx > 1e3f) ? 1 : 0;
}

__global__ void to_bf16(const void* src, size_t elem_off, const int* flag,
                        unsigned short* dst, int n)
{
    const int i = blockIdx.x * 256 + threadIdx.x;
    if (i >= n) return;
    if (*flag) dst[i] = f2bf(((const float*)src)[elem_off + i]);
    else       dst[i] = ((const unsigned short*)src)[elem_off + i];
}

// ---------------------------------------------------------------------------
// Fused prep: init_state (blocks 0..127) + bias/r conversions + r==0 detect
// (blocks 128..131). r-zero detect reads the RAW r inputs (dtype via flag).
// ---------------------------------------------------------------------------
__global__ void prep_small(const void* __restrict__ h0,
                           const void* __restrict__ extra0,
                           const void* __restrict__ b0s, const void* __restrict__ r0s,
                           const void* __restrict__ b1s, const void* __restrict__ r1s,
                           const int* __restrict__ flag,
                           float* __restrict__ state,
                           float* __restrict__ pb,     // b0f,r0f,b1f,r1f (NG each)
                           int* __restrict__ rflag)
{
    const int blk = blockIdx.x;
    const int fl = *flag;

    if (blk < 128) {
        const int idx = blk * 256 + threadIdx.x;  // 0..L*BD
        const int l  = idx / BD;
        const int bd = idx % BD;
        const int b = bd >> 10, d = bd & 1023;
        float* st = state + (size_t)l * 4 * BD;
        const size_t eoff = ((size_t)l * BATCH + b) * (3 * DDIM);
        float cv, nv, mv, hv;
        if (fl) {
            const float* e = (const float*)extra0 + eoff;
            cv = e[d]; nv = e[DDIM + d]; mv = e[2 * DDIM + d];
            hv = ((const float*)h0)[(size_t)l * BD + bd];
        } else {
            const __hip_bfloat16* e = (const __hip_bfloat16*)extra0 + eoff;
            cv = __bfloat162float(e[d]);
            nv = __bfloat162float(e[DDIM + d]);
            mv = __bfloat162float(e[2 * DDIM + d]);
            hv = __bfloat162float(((const __hip_bfloat16*)h0)[(size_t)l * BD + bd]);
        }
        st[0 * BD + bd] = cv;
        st[1 * BD + bd] = nv;
        st[2 * BD + bd] = mv * L2E;   // log2 domain
        st[3 * BD + bd] = hv;
        return;
    }

    // blocks 128..131: convert one NG-vector; 129/131 also detect r==0.
    const int which = blk - 128;              // 0:b0 1:r0 2:b1 3:r1
    const void* src = (which == 0) ? b0s : (which == 1) ? r0s
                    : (which == 2) ? b1s : r1s;
    float* dst = pb + (size_t)which * NG;
    int nz = 0;
#pragma unroll
    for (int j = 0; j < NG / 256; j++) {
        const int i = j * 256 + threadIdx.x;
        float v;
        if (fl) {
            v = ((const float*)src)[i];
            nz |= (v != 0.0f);
        } else {
            const unsigned short u = ((const unsigned short*)src)[i];
            nz |= ((u & 0x7fffu) != 0);
            v = __bfloat162float(((const __hip_bfloat16*)src)[i]);
        }
        dst[i] = v;
    }
    if (which == 1 || which == 3) {
        __shared__ int s[4];
        const int w = threadIdx.x >> 6;
        const int any = __any(nz) ? 1 : 0;
        if ((threadIdx.x & 63) == 0) s[w] = any;
        __syncthreads();
        if (threadIdx.x == 0) rflag[which >> 1] = !(s[0] | s[1] | s[2] | s[3]);
    }
}

// ---------------------------------------------------------------------------
// GEMM with CHAIN-MAJOR, gate-packed, log2-scaled output (round-0 staging:
// single-buffered LDS; the 1.68e7 LDS bank conflicts are accepted — round-1
// A/B showed fixing them costs +1.7%; round-5 showed 2-phase dbuf costs +3.5%).
// Output layout: preT[chain][t] where chain=b*1024+d, 4 gates bf16 = 8B per
// (chain,t); chain stride = tpad=T+PF elems. Scan threads then stream
// SEQUENTIALLY along t (the r4 [t][b][d] layout forced 128KB strides and
// capped passes at 2.4 TB/s). Each 64B line is filled entirely by one block.
// rfast=1: gate0 -> tanh(z_pre), gate3 -> sigmoid(o_pre); gates 1,2 log2-scaled.
// ---------------------------------------------------------------------------
__global__ __launch_bounds__(256, 2)
void gemm_bias(const __hip_bfloat16* __restrict__ A,
               const __hip_bfloat16* __restrict__ W,
               const float* __restrict__ bias,
               unsigned short* __restrict__ out,
               const int* __restrict__ rflag, int tpad)
{
    constexpr int K = 1024;
    __shared__ alignas(16) __hip_bfloat16 sA[128 * 32];
    __shared__ alignas(16) __hip_bfloat16 sB[128 * 32];

    const int t  = threadIdx.x;
    const int m0 = blockIdx.y * 128;
    const int nb = blockIdx.x;          // d-block: d in [nb*32, nb*32+32)
    const int lr = t & 15;
    const int q  = (t >> 4) & 3;
    const int w  = t >> 6;
    const int wm = w >> 1, wn = w & 1;
    const int sr = t >> 2;              // staging row 0..63
    const int sk = (t & 3) * 8;         // staging k-offset (elements)

    floatx4 acc[4][4] = {};

    const __hip_bfloat16* Ab = A + (size_t)(m0 + sr) * K + sk;
    const int wrow = ((sr >> 5) << 10) + nb * 32 + (sr & 31);
    const __hip_bfloat16* Wb = W + (size_t)wrow * K + sk;

    for (int k0 = 0; k0 < K; k0 += 32) {
        __syncthreads();
        __builtin_amdgcn_global_load_lds((as1_void*)(Ab + k0),            (as3_void*)&sA[sr * 32 + sk],        16, 0, 0);
        __builtin_amdgcn_global_load_lds((as1_void*)(Ab + 64 * K + k0),   (as3_void*)&sA[(sr + 64) * 32 + sk], 16, 0, 0);
        __builtin_amdgcn_global_load_lds((as1_void*)(Wb + k0),            (as3_void*)&sB[sr * 32 + sk],        16, 0, 0);
        __builtin_amdgcn_global_load_lds((as1_void*)(Wb + 2048 * K + k0), (as3_void*)&sB[(sr + 64) * 32 + sk], 16, 0, 0);
        __syncthreads();

        short8 af[4], bf[4];
#pragma unroll
        for (int i = 0; i < 4; i++)
            af[i] = *(const short8*)&sA[(wm * 64 + i * 16 + lr) * 32 + q * 8];
#pragma unroll
        for (int j = 0; j < 4; j++)   // j = gate, local d = wn*16 + lr
            bf[j] = *(const short8*)&sB[(j * 32 + wn * 16 + lr) * 32 + q * 8];
#pragma unroll
        for (int i = 0; i < 4; i++)
#pragma unroll
            for (int j = 0; j < 4; j++)
                acc[i][j] = __builtin_amdgcn_mfma_f32_16x16x32_bf16(af[i], bf[j], acc[i][j], 0, 0, 0);
    }

    // epilogue: lane owns d = nb*32 + wn*16 + lr, all 4 gates -> 8B store per
    // (row). row = t*16 + b; write to preT[(b*1024+d)*tpad + trow].
    const int d = nb * 32 + wn * 16 + lr;
    const float sc[4] = {2.0f * L2E, L2E, L2E, L2E};
    float bb[4];
#pragma unroll
    for (int g = 0; g < 4; g++) bb[g] = sc[g] * bias[g * 1024 + d];

    const int rfast = *rflag;   // uniform scalar branch

#pragma unroll
    for (int i = 0; i < 4; i++) {
#pragma unroll
        for (int reg = 0; reg < 4; reg++) {
            const int row = m0 + wm * 64 + i * 16 + q * 4 + reg;
            const int trow = row >> 4;
            const int b    = row & 15;
            float v[4];
#pragma unroll
            for (int g = 0; g < 4; g++)
                v[g] = acc[i][g][reg] * sc[g] + bb[g];
            if (rfast) {
                // gate0 holds 2*L2E*z_pre: tanh(z) = sign*(1-e^-2|z|)/(1+e^-2|z|)
                const float zv = v[0];
                const float e2 = EXP2F(-fabsf(zv));
                v[0] = copysignf((1.0f - e2) * __builtin_amdgcn_rcpf(1.0f + e2), zv);
                // gate3 holds L2E*o_pre: sigmoid
                v[3] = __builtin_amdgcn_rcpf(1.0f + EXP2F(-v[3]));
            }
            union { unsigned short us[4]; uint2 u2; } pk;
#pragma unroll
            for (int g = 0; g < 4; g++) pk.us[g] = f2bf(v[g]);
            const size_t chain = (size_t)((b << 10) + d);
            *(uint2*)(out + (chain * tpad + trow) * 4) = pk.u2;
        }
    }
}

// ---------------------------------------------------------------------------
// Parallel scan over time (rfast only): the r==0 recurrence is associative.
// 1 chain per thread; chain-major pre -> per-thread SEQUENTIAL uint4 stream
// (2 steps / 16B load). NSEG=32 -> 2048 blocks -> 32 waves/CU.
// passA: per (chain, segment) summary (A=sum f, bmax=A+mu, Bhat, Nhat).
// mid:   per chain, compose NSEG summaries sequentially (exact); overwrites
//        smry slots 0..2 with each segment's incoming (c, n, m2).
// passB: per (chain, segment) exact sequential walk emitting h.
// ---------------------------------------------------------------------------
__global__ void scan_passA(const unsigned int* __restrict__ pre,
                           const int* __restrict__ rflag,
                           float* __restrict__ smry, int T, int tpad)
{
    if (!*rflag) return;
    const int gid = blockIdx.x * 256 + threadIdx.x;   // 0..BD*NSEG
    const int chain = gid & (BD - 1);
    const int seg = gid >> 14;
    const int SEG = T / NSEG;
    const int NU  = SEG >> 1;                          // uint4 units (2 steps)

    const uint4* p4 = (const uint4*)((const unsigned long long*)pre
                                     + (size_t)chain * tpad) + seg * NU;

    float al = 0.0f, mu = -3e38f, Bh = 0.0f, Nh = 0.0f;

    uint4 k[PFP];
#pragma unroll
    for (int u = 0; u < PFP; u++) k[u] = p4[u];

    for (int j = 0; j < NU; j += PFP) {
#pragma unroll
        for (int u = 0; u < PFP; u++) {
            const uint4 kv = k[u];
            k[u] = p4[j + u + PFP];
#pragma unroll
            for (int hlf = 0; hlf < 2; hlf++) {
                const unsigned int a = hlf ? kv.z : kv.x;
                const unsigned int bwd = hlf ? kv.w : kv.y;
                const float zt = __uint_as_float(a << 16);        // tanh(z)
                const float i2 = __uint_as_float(a & 0xffff0000u);
                const float f2 = __uint_as_float(bwd << 16);
                al += f2;
                const float e  = i2 - al;
                const float mn = fmaxf(mu, e);
                const float s  = EXP2F(mu - mn);
                const float ww = EXP2F(e - mn);
                Bh = fmaf(Bh, s, ww * zt);
                Nh = fmaf(Nh, s, ww);
                mu = mn;
            }
        }
    }

    smry[0 * NSEG * BD + seg * BD + chain] = al;
    smry[1 * NSEG * BD + seg * BD + chain] = al + mu;   // bmax
    smry[2 * NSEG * BD + seg * BD + chain] = Bh;
    smry[3 * NSEG * BD + seg * BD + chain] = Nh;
}

__global__ void scan_mid(float* __restrict__ smry,
                         const int* __restrict__ rflag,
                         const float* __restrict__ state, int T)
{
    if (!*rflag) return;
    const int idx = blockIdx.x * 256 + threadIdx.x;    // 0..BD
    float c  = state[0 * BD + idx];
    float n  = state[1 * BD + idx];
    float m2 = state[2 * BD + idx];
#pragma unroll
    for (int s = 0; s < NSEG; s++) {
        const float A    = smry[0 * NSEG * BD + s * BD + idx];
        const float bmax = smry[1 * NSEG * BD + s * BD + idx];
        const float Bh   = smry[2 * NSEG * BD + s * BD + idx];
        const float Nh   = smry[3 * NSEG * BD + s * BD + idx];
        // overwrite consumed summary slots with this segment's INCOMING state
        smry[0 * NSEG * BD + s * BD + idx] = c;
        smry[1 * NSEG * BD + s * BD + idx] = n;
        smry[2 * NSEG * BD + s * BD + idx] = m2;
        const float mn = fmaxf(m2 + A, bmax);
        const float sc = EXP2F(m2 + A - mn);
        const float w  = EXP2F(bmax - mn);
        c  = fmaf(sc, c, w * Bh);
        n  = fmaf(sc, n, w * Nh);
        m2 = mn;
    }
}

template<int MODE>
__global__ void scan_passB(const unsigned int* __restrict__ pre,
                           const float* __restrict__ smry,   // seg-init in slots 0..2
                           const int* __restrict__ rflag,
                           float* __restrict__ state,
                           unsigned short* __restrict__ hseq,
                           void* __restrict__ gout, size_t gout_eoff,
                           const int* __restrict__ flag, int T, int tpad)
{
    if (!*rflag) return;
    const int gid = blockIdx.x * 256 + threadIdx.x;
    const int chain = gid & (BD - 1);
    const int seg = gid >> 14;
    const int SEG = T / NSEG;
    const int NU  = SEG >> 1;
    const int t0s = seg * SEG;
    const int fl = *flag;

    float c  = smry[0 * NSEG * BD + seg * BD + chain];
    float n  = smry[1 * NSEG * BD + seg * BD + chain];
    float m2 = smry[2 * NSEG * BD + seg * BD + chain];

    const uint4* p4 = (const uint4*)((const unsigned long long*)pre
                                     + (size_t)chain * tpad) + seg * NU;

    unsigned short* hb = hseq + chain;
    float*          fo = (float*)gout + gout_eoff + chain;
    unsigned short* bo = (unsigned short*)gout + gout_eoff + chain;

    float h = 0.0f;
    uint4 k[PFP];
#pragma unroll
    for (int u = 0; u < PFP; u++) k[u] = p4[u];

    for (int j = 0; j < NU; j += PFP) {
#pragma unroll
        for (int u = 0; u < PFP; u++) {
            const uint4 kv = k[u];
            k[u] = p4[j + u + PFP];
#pragma unroll
            for (int hlf = 0; hlf < 2; hlf++) {
                const unsigned int a = hlf ? kv.z : kv.x;
                const unsigned int bwd = hlf ? kv.w : kv.y;
                const float zt = __uint_as_float(a << 16);         // tanh(z)
                const float i2 = __uint_as_float(a & 0xffff0000u);
                const float f2 = __uint_as_float(bwd << 16);
                const float ot = __uint_as_float(bwd & 0xffff0000u); // sigmoid(o)

                const float fm = f2 + m2;
                const float mn = fmaxf(fm, i2);
                const float ft = EXP2F(fm - mn);
                const float it = EXP2F(i2 - mn);

                c  = fmaf(ft, c, it * zt);
                n  = fmaf(ft, n, it);
                m2 = mn;
                h  = ot * c * __builtin_amdgcn_rcpf(fabsf(n) + 1e-6f);

                const size_t toff = (size_t)(t0s + 2 * (j + u) + hlf) * BD;
                if (MODE == 0)      hb[toff] = f2bf(h);
                else if (fl)        fo[toff] = h;
                else                bo[toff] = f2bf(h);
            }
        }
    }

    if (seg == NSEG - 1) {
        state[0 * BD + chain] = c;
        state[1 * BD + chain] = n;
        state[2 * BD + chain] = m2;
        state[3 * BD + chain] = h;
    }
}

// ---------------------------------------------------------------------------
// Sequential sLSTM scan — general fallback (handles r != 0). When pgate=1 and
// rflag=1 the parallel path owns this layer and this kernel early-exits.
// Chain-major pre: per-thread sequential uint2 walk.
// ---------------------------------------------------------------------------
template<int MODE>
__global__ void slstm_scan(const unsigned int* __restrict__ pre,
                           const float* __restrict__ r,
                           float* __restrict__ state,
                           unsigned short* __restrict__ hseq,
                           void* __restrict__ gout, size_t gout_eoff,
                           const int* __restrict__ flag,
                           const int* __restrict__ rflag, int T, int tpad,
                           int pgate)
{
    const int rfast = *rflag;
    if (pgate && rfast) return;

    const int idx = blockIdx.x * 64 + threadIdx.x;  // 0..BD (chain)
    const int d = idx & 1023;
    const int fl = *flag;

    const float rz = r[d]            * (2.0f * L2E);
    const float ri = r[DDIM + d]     * L2E;
    const float rf = r[2 * DDIM + d] * L2E;
    const float ro = r[3 * DDIM + d] * L2E;

    float c  = state[0 * BD + idx];
    float n  = state[1 * BD + idx];
    float m2 = state[2 * BD + idx];   // log2 domain
    float h  = state[3 * BD + idx];

    const uint2* p = (const uint2*)((const unsigned long long*)pre
                                    + (size_t)idx * tpad);

    unsigned short* hb = hseq + idx;
    float*          fo = (float*)gout + gout_eoff + idx;
    unsigned short* bo = (unsigned short*)gout + gout_eoff + idx;

    unsigned int k0[PF], k1[PF];
#pragma unroll
    for (int u = 0; u < PF; u++) {
        const uint2 v = p[u];
        k0[u] = v.x; k1[u] = v.y;
    }

    if (rfast) {
        for (int t8 = 0; t8 < T; t8 += PF) {
#pragma unroll
            for (int u = 0; u < PF; u++) {
                const float zt = __uint_as_float(k0[u] << 16);
                const float i2 = __uint_as_float(k0[u] & 0xffff0000u);
                const float f2 = __uint_as_float(k1[u] << 16);
                const float ot = __uint_as_float(k1[u] & 0xffff0000u);

                const uint2 nv = p[t8 + u + PF];
                k0[u] = nv.x; k1[u] = nv.y;

                const float fm = f2 + m2;
                const float mn = fmaxf(fm, i2);
                const float ft = EXP2F(fm - mn);
                const float it = EXP2F(i2 - mn);

                c  = fmaf(ft, c, it * zt);
                n  = fmaf(ft, n, it);
                m2 = mn;
                h  = ot * c * __builtin_amdgcn_rcpf(fabsf(n) + 1e-6f);

                const size_t toff = (size_t)(t8 + u) * BD;
                if (MODE == 0)      hb[toff] = f2bf(h);
                else if (fl)        fo[toff] = h;
                else                bo[toff] = f2bf(h);
            }
        }
    } else {
        for (int t8 = 0; t8 < T; t8 += PF) {
#pragma unroll
            for (int u = 0; u < PF; u++) {
                float z2 = __uint_as_float(k0[u] << 16);
                float i2 = __uint_as_float(k0[u] & 0xffff0000u);
                float f2 = __uint_as_float(k1[u] << 16);
                float o2 = __uint_as_float(k1[u] & 0xffff0000u);

                const uint2 nv = p[t8 + u + PF];
                k0[u] = nv.x; k1[u] = nv.y;

                z2 = fmaf(rz, h, z2);
                i2 = fmaf(ri, h, i2);
                f2 = fmaf(rf, h, f2);
                o2 = fmaf(ro, h, o2);

                const float fm = f2 + m2;
                const float mn = fmaxf(fm, i2);
                const float ft = EXP2F(fm - mn);   // <= 1
                const float it = EXP2F(i2 - mn);   // <= 1

                const float e2 = EXP2F(-fabsf(z2));
                const float zt = copysignf((1.0f - e2) * __builtin_amdgcn_rcpf(1.0f + e2), z2);
                const float ot = __builtin_amdgcn_rcpf(1.0f + EXP2F(-o2));

                c  = ft * c + it * zt;
                n  = ft * n + it;
                m2 = mn;
                h  = ot * c * __builtin_amdgcn_rcpf(fabsf(n) + 1e-6f);

                const size_t toff = (size_t)(t8 + u) * BD;
                if (MODE == 0)      hb[toff] = f2bf(h);
                else if (fl)        fo[toff] = h;
                else                bo[toff] = f2bf(h);
            }
        }
    }

    state[0 * BD + idx] = c;
    state[1 * BD + idx] = n;
    state[2 * BD + idx] = m2;
    state[3 * BD + idx] = h;
}

// ---------------------------------------------------------------------------
__global__ void finalize(const float* __restrict__ state,
                         void* __restrict__ out,
                         const int* __restrict__ flag)
{
    const int idx = blockIdx.x * 256 + threadIdx.x;  // 0..L*BD
    const int l  = idx / BD;
    const int bd = idx % BD;
    const int b = bd >> 10, d = bd & 1023;
    const float* st = state + (size_t)l * 4 * BD;
    const float cv = st[0 * BD + bd], nv = st[1 * BD + bd];
    const float mv = st[2 * BD + bd] * LN2;          // back from log2 domain
    const float hv = st[3 * BD + bd];

    const size_t hoff = (size_t)S_LEN * BD + idx;
    const size_t eoff = (size_t)S_LEN * BD + (size_t)LAYERS * BD
                      + ((size_t)l * BATCH + b) * (3 * DDIM);
    if (*flag) {
        float* o = (float*)out;
        o[hoff] = hv;
        o[eoff + d] = cv; o[eoff + DDIM + d] = nv; o[eoff + 2 * DDIM + d] = mv;
    } else {
        unsigned short* o = (unsigned short*)out;
        o[hoff] = f2bf(hv);
        o[eoff + d]            = f2bf(cv);
        o[eoff + DDIM + d]     = f2bf(nv);
        o[eoff + 2 * DDIM + d] = f2bf(mv);
    }
}

__global__ void zero_out_k(void* __restrict__ out, const int* __restrict__ flag,
                           int out_size)
{
    const size_t i = (size_t)blockIdx.x * 256 + threadIdx.x;
    const size_t nb = (size_t)out_size * ((*flag) ? 4 : 2);
    char* o = (char*)out;
    for (size_t j = i * 4; j < (i + 1) * 4 && j < nb; j++) o[j] = 0;
}

// ---------------------------------------------------------------------------
extern "C" void kernel_launch(void* const* d_in, const int* in_sizes, int n_in,
                              void* d_out, int out_size, void* d_ws, size_t ws_size,
                              hipStream_t stream)
{
    const void* input  = d_in[0];
    const void* h0     = d_in[1];
    const void* extra0 = d_in[2];
    const void* W0     = d_in[3];
    const void* b0     = d_in[4];
    const void* r0     = d_in[5];
    const void* W1     = d_in[6];
    const void* b1     = d_in[7];
    const void* r1     = d_in[8];

    const size_t FLAG_B  = 256;
    const size_t STATE_B = (size_t)LAYERS * 4 * BD * 4;   // 512 KB
    const size_t W_B     = (size_t)NG * IDIM * 2;          // 8 MB each
    const size_t PB_B    = (size_t)4 * NG * 4;             // 64 KB
    const size_t SM_B    = (size_t)4 * NSEG * BD * 4;      // 8 MB (summaries + seg-init)
    const size_t FIXED   = FLAG_B + STATE_B + 2 * W_B + PB_B + SM_B;

    int T = 0;
    for (int cand = S_LEN; cand >= 8; cand >>= 1) {
        size_t need = FIXED
                    + (size_t)cand * BD * 2                   // Ain  (bf16)
                    + (size_t)cand * BD * 2                   // hseq (bf16)
                    + (size_t)(cand + PF) * BD * 8;           // preT (chain-major)
        if (need <= ws_size) { T = cand; break; }
    }

    char* ws = (char*)d_ws;
    int*   flag  = (int*)ws;
    int*   rflag = flag + 1;                               // rflag[0], rflag[1]
    float* state = (float*)(ws + FLAG_B);
    __hip_bfloat16* W0b = (__hip_bfloat16*)(ws + FLAG_B + STATE_B);
    __hip_bfloat16* W1b = W0b + (size_t)NG * IDIM;
    float* pb    = (float*)(ws + FLAG_B + STATE_B + 2 * W_B);
    float* b0f = pb, *r0f = pb + NG, *b1f = pb + 2 * NG, *r1f = pb + 3 * NG;
    float* smry  = (float*)(ws + FLAG_B + STATE_B + 2 * W_B + PB_B);
    unsigned short* Ain  = (unsigned short*)(ws + FIXED);
    unsigned short* hseq = Ain + (size_t)T * BD;
    unsigned short* pre  = hseq + (size_t)T * BD;

    detect_dtype<<<dim3(1), dim3(64), 0, stream>>>(W0, flag);

    if (T == 0) {
        zero_out_k<<<dim3((out_size + 255) / 256), dim3(256), 0, stream>>>(d_out, flag, out_size);
        return;
    }

    const int WN = NG * IDIM;
    to_bf16<<<dim3(WN / 256), dim3(256), 0, stream>>>(W0, 0, flag, (unsigned short*)W0b, WN);
    to_bf16<<<dim3(WN / 256), dim3(256), 0, stream>>>(W1, 0, flag, (unsigned short*)W1b, WN);

    prep_small<<<dim3(132), dim3(256), 0, stream>>>(h0, extra0, b0, r0, b1, r1,
                                                    flag, state, pb, rflag);

    const int  tpad = T + PF;
    const dim3 gemmGrid(32, (T * BATCH) / 128);
    const dim3 scanGrid(BD / 64);
    const dim3 passGrid((BD * NSEG) / 256);
    const dim3 midGrid(BD / 256);
    const int  nch = S_LEN / T;
    // parallel path needs SEG = T/NSEG to be a positive multiple of 16
    const int  useP = (T >= 512 && (T % (NSEG * 16)) == 0) ? 1 : 0;

    for (int ch = 0; ch < nch; ch++) {
        const int t0 = ch * T;

        to_bf16<<<dim3((T * BD) / 256), dim3(256), 0, stream>>>(
            input, (size_t)t0 * BD, flag, Ain, T * BD);

        // ---- layer 0 ----
        gemm_bias<<<gemmGrid, 256, 0, stream>>>((const __hip_bfloat16*)Ain, W0b, b0f, pre, rflag + 0, tpad);
        if (useP) {
            scan_passA<<<passGrid, 256, 0, stream>>>((const unsigned int*)pre, rflag + 0, smry, T, tpad);
            scan_mid<<<midGrid, 256, 0, stream>>>(smry, rflag + 0, state, T);
            scan_passB<0><<<passGrid, 256, 0, stream>>>((const unsigned int*)pre, smry, rflag + 0,
                                                        state, hseq, (void*)0, 0, flag, T, tpad);
        }
        slstm_scan<0><<<scanGrid, 64, 0, stream>>>((const unsigned int*)pre, r0f, state,
                                                   hseq, (void*)0, 0, flag, rflag + 0, T, tpad, useP);

        // ---- layer 1 ----
        gemm_bias<<<gemmGrid, 256, 0, stream>>>((const __hip_bfloat16*)hseq, W1b, b1f, pre, rflag + 1, tpad);
        if (useP) {
            scan_passA<<<passGrid, 256, 0, stream>>>((const unsigned int*)pre, rflag + 1, smry, T, tpad);
            scan_mid<<<midGrid, 256, 0, stream>>>(smry, rflag + 1, state + 4 * BD, T);
            scan_passB<1><<<passGrid, 256, 0, stream>>>((const unsigned int*)pre, smry, rflag + 1,
                                                        state + 4 * BD, (unsigned short*)0,
                                                        d_out, (size_t)t0 * BD, flag, T, tpad);
        }
        slstm_scan<1><<<scanGrid, 64, 0, stream>>>((const unsigned int*)pre, r1f,
                                                   state + 4 * BD, (unsigned short*)0,
                                                   d_out, (size_t)t0 * BD, flag, rflag + 1, T, tpad, useP);
    }

    finalize<<<dim3(LAYERS * BD / 256), dim3(256), 0, stream>>>(state, d_out, flag);
}

// Round 7
// 672.070 us; speedup vs baseline: 1.1169x; 1.1169x over previous
//
#include <hip/hip_runtime.h>
#include <hip/hip_bf16.h>

#define S_LEN  1024
#define BATCH  16
#define IDIM   1024
#define DDIM   1024
#define NG     4096     // 4*DDIM
#define BD     16384    // BATCH*DDIM
#define LAYERS 2
#define PF     16       // seq-scan prefetch depth (pre has PF extra steps pad)
#define PFP    8        // parallel-pass prefetch depth
#define NSEG   32       // time segments for the parallel scan

typedef __attribute__((ext_vector_type(8))) short   short8;
typedef __attribute__((ext_vector_type(4))) float   floatx4;
typedef __attribute__((address_space(1))) void      as1_void;
typedef __attribute__((address_space(3))) void      as3_void;

#define L2E  1.4426950408889634f   // log2(e)
#define LN2  0.6931471805599453f

#define EXP2F(x) exp2f(x)

// RNE f32->bf16, 3 ops (NaN irrelevant here)
static __device__ __forceinline__ unsigned short f2bf(float x) {
    unsigned int u = __float_as_uint(x);
    return (unsigned short)((u + 0x7fffu + ((u >> 16) & 1u)) >> 16);
}

// ---------------------------------------------------------------------------
// Dtype detect: read W0 head AS bf16; f32 garbage -> max |v| huge.
// flag: 1 = f32 I/O, 0 = bf16 I/O.
// ---------------------------------------------------------------------------
__global__ void detect_dtype(const void* w, int* flag)
{
    const __hip_bfloat16* p = (const __hip_bfloat16*)w;
    float mx = 0.0f;
    for (int i = threadIdx.x; i < 4096; i += 64) {
        float v = __bfloat162float(p[i]);
        float a = fabsf(v);
        if (!(a == a)) a = 1e30f;
        mx = fmaxf(mx, a);
    }
#pragma unroll
    for (int o = 32; o > 0; o >>= 1)
        mx = fmaxf(mx, __shfl_down(mx, o, 64));
    if (threadIdx.x == 0) *flag = (mx > 1e3f) ? 1 : 0;
}

__global__ void to_bf16(const void* src, size_t elem_off, const int* flag,
                        unsigned short* dst, int n)
{
    const int i = blockIdx.x * 256 + threadIdx.x;
    if (i >= n) return;
    if (*flag) dst[i] = f2bf(((const float*)src)[elem_off + i]);
    else       dst[i] = ((const unsigned short*)src)[elem_off + i];
}

// ---------------------------------------------------------------------------
// Fused prep: init_state (blocks 0..127) + bias/r conversions + r==0 detect
// (blocks 128..131). r-zero detect reads the RAW r inputs (dtype via flag).
// ---------------------------------------------------------------------------
__global__ void prep_small(const void* __restrict__ h0,
                           const void* __restrict__ extra0,
                           const void* __restrict__ b0s, const void* __restrict__ r0s,
                           const void* __restrict__ b1s, const void* __restrict__ r1s,
                           const int* __restrict__ flag,
                           float* __restrict__ state,
                           float* __restrict__ pb,     // b0f,r0f,b1f,r1f (NG each)
                           int* __restrict__ rflag)
{
    const int blk = blockIdx.x;
    const int fl = *flag;

    if (blk < 128) {
        const int idx = blk * 256 + threadIdx.x;  // 0..L*BD
        const int l  = idx / BD;
        const int bd = idx % BD;
        const int b = bd >> 10, d = bd & 1023;
        float* st = state + (size_t)l * 4 * BD;
        const size_t eoff = ((size_t)l * BATCH + b) * (3 * DDIM);
        float cv, nv, mv, hv;
        if (fl) {
            const float* e = (const float*)extra0 + eoff;
            cv = e[d]; nv = e[DDIM + d]; mv = e[2 * DDIM + d];
            hv = ((const float*)h0)[(size_t)l * BD + bd];
        } else {
            const __hip_bfloat16* e = (const __hip_bfloat16*)extra0 + eoff;
            cv = __bfloat162float(e[d]);
            nv = __bfloat162float(e[DDIM + d]);
            mv = __bfloat162float(e[2 * DDIM + d]);
            hv = __bfloat162float(((const __hip_bfloat16*)h0)[(size_t)l * BD + bd]);
        }
        st[0 * BD + bd] = cv;
        st[1 * BD + bd] = nv;
        st[2 * BD + bd] = mv * L2E;   // log2 domain
        st[3 * BD + bd] = hv;
        return;
    }

    // blocks 128..131: convert one NG-vector; 129/131 also detect r==0.
    const int which = blk - 128;              // 0:b0 1:r0 2:b1 3:r1
    const void* src = (which == 0) ? b0s : (which == 1) ? r0s
                    : (which == 2) ? b1s : r1s;
    float* dst = pb + (size_t)which * NG;
    int nz = 0;
#pragma unroll
    for (int j = 0; j < NG / 256; j++) {
        const int i = j * 256 + threadIdx.x;
        float v;
        if (fl) {
            v = ((const float*)src)[i];
            nz |= (v != 0.0f);
        } else {
            const unsigned short u = ((const unsigned short*)src)[i];
            nz |= ((u & 0x7fffu) != 0);
            v = __bfloat162float(((const __hip_bfloat16*)src)[i]);
        }
        dst[i] = v;
    }
    if (which == 1 || which == 3) {
        __shared__ int s[4];
        const int w = threadIdx.x >> 6;
        const int any = __any(nz) ? 1 : 0;
        if ((threadIdx.x & 63) == 0) s[w] = any;
        __syncthreads();
        if (threadIdx.x == 0) rflag[which >> 1] = !(s[0] | s[1] | s[2] | s[3]);
    }
}

// ---------------------------------------------------------------------------
// GEMM with gate-interleaved, log2-scaled output — round-4 form (best: 173.5us).
// [t][chain] output layout: pre[row*4096 + d*4 + g], row = t*16+b. This is
// wave-coalesced on BOTH the gemm write (8B x 64 lanes contiguous in d) and
// the scan read (adjacent lanes = adjacent d). Round-6 chain-major A/B:
// WRITE_SIZE 131072->218000 KB (partial-line RMW), gemm +48us — reverted.
// 1.68e7 LDS bank conflicts accepted (round-1 A/B: fixing cost +1.7%);
// single-buffer LDS (round-5 A/B: 2-phase dbuf cost +3.5%).
// rfast=1: gate0 -> tanh(z_pre), gate3 -> sigmoid(o_pre); gates 1,2 log2-scaled.
// ---------------------------------------------------------------------------
__global__ __launch_bounds__(256, 2)
void gemm_bias(const __hip_bfloat16* __restrict__ A,
               const __hip_bfloat16* __restrict__ W,
               const float* __restrict__ bias,
               unsigned short* __restrict__ out,
               const int* __restrict__ rflag)
{
    constexpr int K = 1024;
    __shared__ alignas(16) __hip_bfloat16 sA[128 * 32];
    __shared__ alignas(16) __hip_bfloat16 sB[128 * 32];

    const int t  = threadIdx.x;
    const int m0 = blockIdx.y * 128;
    const int nb = blockIdx.x;          // d-block: d in [nb*32, nb*32+32)
    const int lr = t & 15;
    const int q  = (t >> 4) & 3;
    const int w  = t >> 6;
    const int wm = w >> 1, wn = w & 1;
    const int sr = t >> 2;              // staging row 0..63
    const int sk = (t & 3) * 8;         // staging k-offset (elements)

    floatx4 acc[4][4] = {};

    const __hip_bfloat16* Ab = A + (size_t)(m0 + sr) * K + sk;
    const int wrow = ((sr >> 5) << 10) + nb * 32 + (sr & 31);
    const __hip_bfloat16* Wb = W + (size_t)wrow * K + sk;

    for (int k0 = 0; k0 < K; k0 += 32) {
        __syncthreads();
        __builtin_amdgcn_global_load_lds((as1_void*)(Ab + k0),            (as3_void*)&sA[sr * 32 + sk],        16, 0, 0);
        __builtin_amdgcn_global_load_lds((as1_void*)(Ab + 64 * K + k0),   (as3_void*)&sA[(sr + 64) * 32 + sk], 16, 0, 0);
        __builtin_amdgcn_global_load_lds((as1_void*)(Wb + k0),            (as3_void*)&sB[sr * 32 + sk],        16, 0, 0);
        __builtin_amdgcn_global_load_lds((as1_void*)(Wb + 2048 * K + k0), (as3_void*)&sB[(sr + 64) * 32 + sk], 16, 0, 0);
        __syncthreads();

        short8 af[4], bf[4];
#pragma unroll
        for (int i = 0; i < 4; i++)
            af[i] = *(const short8*)&sA[(wm * 64 + i * 16 + lr) * 32 + q * 8];
#pragma unroll
        for (int j = 0; j < 4; j++)   // j = gate, local d = wn*16 + lr
            bf[j] = *(const short8*)&sB[(j * 32 + wn * 16 + lr) * 32 + q * 8];
#pragma unroll
        for (int i = 0; i < 4; i++)
#pragma unroll
            for (int j = 0; j < 4; j++)
                acc[i][j] = __builtin_amdgcn_mfma_f32_16x16x32_bf16(af[i], bf[j], acc[i][j], 0, 0, 0);
    }

    // epilogue: lane owns d = nb*32 + wn*16 + lr, all 4 gates -> 8B stores
    const int d = nb * 32 + wn * 16 + lr;
    const float sc[4] = {2.0f * L2E, L2E, L2E, L2E};
    float bb[4];
#pragma unroll
    for (int g = 0; g < 4; g++) bb[g] = sc[g] * bias[g * 1024 + d];

    const int rfast = *rflag;   // uniform scalar branch

#pragma unroll
    for (int i = 0; i < 4; i++) {
#pragma unroll
        for (int reg = 0; reg < 4; reg++) {
            const int row = m0 + wm * 64 + i * 16 + q * 4 + reg;
            float v[4];
#pragma unroll
            for (int g = 0; g < 4; g++)
                v[g] = acc[i][g][reg] * sc[g] + bb[g];
            if (rfast) {
                // gate0 holds 2*L2E*z_pre: tanh(z) = sign*(1-e^-2|z|)/(1+e^-2|z|)
                const float zv = v[0];
                const float e2 = EXP2F(-fabsf(zv));
                v[0] = copysignf((1.0f - e2) * __builtin_amdgcn_rcpf(1.0f + e2), zv);
                // gate3 holds L2E*o_pre: sigmoid
                v[3] = __builtin_amdgcn_rcpf(1.0f + EXP2F(-v[3]));
            }
            union { unsigned short us[4]; uint2 u2; } pk;
#pragma unroll
            for (int g = 0; g < 4; g++) pk.us[g] = f2bf(v[g]);
            *(uint2*)(out + (size_t)row * NG + d * 4) = pk.u2;
        }
    }
}

// ---------------------------------------------------------------------------
// Parallel scan over time (rfast only): the r==0 recurrence is associative.
// [t][chain] layout: adjacent lanes read adjacent chains -> coalesced 512B
// per wave instruction. NSEG=32, 1 chain/thread -> 2048 blocks = 32 waves/CU
// (round-4's 2.4 TB/s was 1-2 waves/CU occupancy, not layout).
// passA: per (chain, segment) summary (A=sum f, bmax=A+mu, Bhat, Nhat).
// mid:   per chain, compose NSEG summaries sequentially (exact); overwrites
//        smry slots 0..2 with each segment's incoming (c, n, m2).
// passB: per (chain, segment) exact sequential walk emitting h.
// ---------------------------------------------------------------------------
__global__ void scan_passA(const unsigned int* __restrict__ pre,
                           const int* __restrict__ rflag,
                           float* __restrict__ smry, int T)
{
    if (!*rflag) return;
    const int gid = blockIdx.x * 256 + threadIdx.x;   // 0..BD*NSEG
    const int chain = gid & (BD - 1);
    const int seg = gid >> 14;
    const int SEG = T / NSEG;
    const int b = chain >> 10, d = chain & 1023;

    const size_t stp = 32768;                          // uints per timestep
    const unsigned int* p = pre + (size_t)b * 2048 + (size_t)d * 2
                              + (size_t)(seg * SEG) * stp;

    float al = 0.0f, mu = -3e38f, Bh = 0.0f, Nh = 0.0f;

    unsigned int k0[PFP], k1[PFP];
#pragma unroll
    for (int u = 0; u < PFP; u++) {
        const uint2 v = *(const uint2*)(p + (size_t)u * stp);
        k0[u] = v.x; k1[u] = v.y;
    }

    for (int t = 0; t < SEG; t += PFP) {
#pragma unroll
        for (int u = 0; u < PFP; u++) {
            const float zt = __uint_as_float(k0[u] << 16);        // tanh(z)
            const float i2 = __uint_as_float(k0[u] & 0xffff0000u);
            const float f2 = __uint_as_float(k1[u] << 16);

            const uint2 nv = *(const uint2*)(p + (size_t)(t + u + PFP) * stp);
            k0[u] = nv.x; k1[u] = nv.y;

            al += f2;
            const float e  = i2 - al;
            const float mn = fmaxf(mu, e);
            const float s  = EXP2F(mu - mn);
            const float ww = EXP2F(e - mn);
            Bh = fmaf(Bh, s, ww * zt);
            Nh = fmaf(Nh, s, ww);
            mu = mn;
        }
    }

    smry[0 * NSEG * BD + seg * BD + chain] = al;
    smry[1 * NSEG * BD + seg * BD + chain] = al + mu;   // bmax
    smry[2 * NSEG * BD + seg * BD + chain] = Bh;
    smry[3 * NSEG * BD + seg * BD + chain] = Nh;
}

__global__ void scan_mid(float* __restrict__ smry,
                         const int* __restrict__ rflag,
                         const float* __restrict__ state, int T)
{
    if (!*rflag) return;
    const int idx = blockIdx.x * 256 + threadIdx.x;    // 0..BD
    float c  = state[0 * BD + idx];
    float n  = state[1 * BD + idx];
    float m2 = state[2 * BD + idx];
#pragma unroll
    for (int s = 0; s < NSEG; s++) {
        const float A    = smry[0 * NSEG * BD + s * BD + idx];
        const float bmax = smry[1 * NSEG * BD + s * BD + idx];
        const float Bh   = smry[2 * NSEG * BD + s * BD + idx];
        const float Nh   = smry[3 * NSEG * BD + s * BD + idx];
        // overwrite consumed summary slots with this segment's INCOMING state
        smry[0 * NSEG * BD + s * BD + idx] = c;
        smry[1 * NSEG * BD + s * BD + idx] = n;
        smry[2 * NSEG * BD + s * BD + idx] = m2;
        const float mn = fmaxf(m2 + A, bmax);
        const float sc = EXP2F(m2 + A - mn);
        const float w  = EXP2F(bmax - mn);
        c  = fmaf(sc, c, w * Bh);
        n  = fmaf(sc, n, w * Nh);
        m2 = mn;
    }
}

template<int MODE>
__global__ void scan_passB(const unsigned int* __restrict__ pre,
                           const float* __restrict__ smry,   // seg-init in slots 0..2
                           const int* __restrict__ rflag,
                           float* __restrict__ state,
                           unsigned short* __restrict__ hseq,
                           void* __restrict__ gout, size_t gout_eoff,
                           const int* __restrict__ flag, int T)
{
    if (!*rflag) return;
    const int gid = blockIdx.x * 256 + threadIdx.x;
    const int chain = gid & (BD - 1);
    const int seg = gid >> 14;
    const int SEG = T / NSEG;
    const int t0s = seg * SEG;
    const int b = chain >> 10, d = chain & 1023;
    const int fl = *flag;

    float c  = smry[0 * NSEG * BD + seg * BD + chain];
    float n  = smry[1 * NSEG * BD + seg * BD + chain];
    float m2 = smry[2 * NSEG * BD + seg * BD + chain];

    const size_t stp = 32768;
    const unsigned int* p = pre + (size_t)b * 2048 + (size_t)d * 2
                              + (size_t)t0s * stp;

    unsigned short* hb = hseq + (size_t)b * DDIM + d + (size_t)t0s * BD;
    float*          fo = (float*)gout + gout_eoff + (size_t)b * DDIM + d + (size_t)t0s * BD;
    unsigned short* bo = (unsigned short*)gout + gout_eoff + (size_t)b * DDIM + d + (size_t)t0s * BD;

    float h = 0.0f;
    unsigned int k0[PFP], k1[PFP];
#pragma unroll
    for (int u = 0; u < PFP; u++) {
        const uint2 v = *(const uint2*)(p + (size_t)u * stp);
        k0[u] = v.x; k1[u] = v.y;
    }

    for (int t = 0; t < SEG; t += PFP) {
#pragma unroll
        for (int u = 0; u < PFP; u++) {
            const float zt = __uint_as_float(k0[u] << 16);        // tanh(z)
            const float i2 = __uint_as_float(k0[u] & 0xffff0000u);
            const float f2 = __uint_as_float(k1[u] << 16);
            const float ot = __uint_as_float(k1[u] & 0xffff0000u); // sigmoid(o)

            const uint2 nv = *(const uint2*)(p + (size_t)(t + u + PFP) * stp);
            k0[u] = nv.x; k1[u] = nv.y;

            const float fm = f2 + m2;
            const float mn = fmaxf(fm, i2);
            const float ft = EXP2F(fm - mn);
            const float it = EXP2F(i2 - mn);

            c  = fmaf(ft, c, it * zt);
            n  = fmaf(ft, n, it);
            m2 = mn;
            h  = ot * c * __builtin_amdgcn_rcpf(fabsf(n) + 1e-6f);

            const size_t toff = (size_t)(t + u) * BD;
            if (MODE == 0)      hb[toff] = f2bf(h);
            else if (fl)        fo[toff] = h;
            else                bo[toff] = f2bf(h);
        }
    }

    if (seg == NSEG - 1) {
        state[0 * BD + chain] = c;
        state[1 * BD + chain] = n;
        state[2 * BD + chain] = m2;
        state[3 * BD + chain] = h;
    }
}

// ---------------------------------------------------------------------------
// Sequential sLSTM scan — general fallback (handles r != 0). When pgate=1 and
// rflag=1 the parallel path owns this layer and this kernel early-exits.
// ---------------------------------------------------------------------------
template<int MODE>
__global__ void slstm_scan(const unsigned int* __restrict__ pre,  // uint view
                           const float* __restrict__ r,
                           float* __restrict__ state,
                           unsigned short* __restrict__ hseq,
                           void* __restrict__ gout, size_t gout_eoff,
                           const int* __restrict__ flag,
                           const int* __restrict__ rflag, int T, int pgate)
{
    const int rfast = *rflag;
    if (pgate && rfast) return;

    const int idx = blockIdx.x * 64 + threadIdx.x;  // 0..BD
    const int b = idx >> 10;
    const int d = idx & 1023;
    const int fl = *flag;

    const float rz = r[d]            * (2.0f * L2E);
    const float ri = r[DDIM + d]     * L2E;
    const float rf = r[2 * DDIM + d] * L2E;
    const float ro = r[3 * DDIM + d] * L2E;

    float c  = state[0 * BD + idx];
    float n  = state[1 * BD + idx];
    float m2 = state[2 * BD + idx];   // log2 domain
    float h  = state[3 * BD + idx];

    const size_t stp = 32768;         // uints per timestep (B*4096 ushorts)
    const unsigned int* p = pre + (size_t)b * 2048 + (size_t)d * 2;

    unsigned short* hb = hseq + (size_t)b * DDIM + d;
    float*          fo = (float*)gout + gout_eoff + (size_t)b * DDIM + d;
    unsigned short* bo = (unsigned short*)gout + gout_eoff + (size_t)b * DDIM + d;

    unsigned int k0[PF], k1[PF];
#pragma unroll
    for (int u = 0; u < PF; u++) {
        const uint2 v = *(const uint2*)(p + (size_t)u * stp);
        k0[u] = v.x; k1[u] = v.y;
    }

    if (rfast) {
        for (int t8 = 0; t8 < T; t8 += PF) {
#pragma unroll
            for (int u = 0; u < PF; u++) {
                const float zt = __uint_as_float(k0[u] << 16);
                const float i2 = __uint_as_float(k0[u] & 0xffff0000u);
                const float f2 = __uint_as_float(k1[u] << 16);
                const float ot = __uint_as_float(k1[u] & 0xffff0000u);

                const uint2 nv = *(const uint2*)(p + (size_t)(t8 + u + PF) * stp);
                k0[u] = nv.x; k1[u] = nv.y;

                const float fm = f2 + m2;
                const float mn = fmaxf(fm, i2);
                const float ft = EXP2F(fm - mn);
                const float it = EXP2F(i2 - mn);

                c  = fmaf(ft, c, it * zt);
                n  = fmaf(ft, n, it);
                m2 = mn;
                h  = ot * c * __builtin_amdgcn_rcpf(fabsf(n) + 1e-6f);

                const size_t toff = (size_t)(t8 + u) * BD;
                if (MODE == 0)      hb[toff] = f2bf(h);
                else if (fl)        fo[toff] = h;
                else                bo[toff] = f2bf(h);
            }
        }
    } else {
        for (int t8 = 0; t8 < T; t8 += PF) {
#pragma unroll
            for (int u = 0; u < PF; u++) {
                float z2 = __uint_as_float(k0[u] << 16);
                float i2 = __uint_as_float(k0[u] & 0xffff0000u);
                float f2 = __uint_as_float(k1[u] << 16);
                float o2 = __uint_as_float(k1[u] & 0xffff0000u);

                const uint2 nv = *(const uint2*)(p + (size_t)(t8 + u + PF) * stp);
                k0[u] = nv.x; k1[u] = nv.y;

                z2 = fmaf(rz, h, z2);
                i2 = fmaf(ri, h, i2);
                f2 = fmaf(rf, h, f2);
                o2 = fmaf(ro, h, o2);

                const float fm = f2 + m2;
                const float mn = fmaxf(fm, i2);
                const float ft = EXP2F(fm - mn);   // <= 1
                const float it = EXP2F(i2 - mn);   // <= 1

                const float e2 = EXP2F(-fabsf(z2));
                const float zt = copysignf((1.0f - e2) * __builtin_amdgcn_rcpf(1.0f + e2), z2);
                const float ot = __builtin_amdgcn_rcpf(1.0f + EXP2F(-o2));

                c  = ft * c + it * zt;
                n  = ft * n + it;
                m2 = mn;
                h  = ot * c * __builtin_amdgcn_rcpf(fabsf(n) + 1e-6f);

                const size_t toff = (size_t)(t8 + u) * BD;
                if (MODE == 0)      hb[toff] = f2bf(h);
                else if (fl)        fo[toff] = h;
                else                bo[toff] = f2bf(h);
            }
        }
    }

    state[0 * BD + idx] = c;
    state[1 * BD + idx] = n;
    state[2 * BD + idx] = m2;
    state[3 * BD + idx] = h;
}

// ---------------------------------------------------------------------------
__global__ void finalize(const float* __restrict__ state,
                         void* __restrict__ out,
                         const int* __restrict__ flag)
{
    const int idx = blockIdx.x * 256 + threadIdx.x;  // 0..L*BD
    const int l  = idx / BD;
    const int bd = idx % BD;
    const int b = bd >> 10, d = bd & 1023;
    const float* st = state + (size_t)l * 4 * BD;
    const float cv = st[0 * BD + bd], nv = st[1 * BD + bd];
    const float mv = st[2 * BD + bd] * LN2;          // back from log2 domain
    const float hv = st[3 * BD + bd];

    const size_t hoff = (size_t)S_LEN * BD + idx;
    const size_t eoff = (size_t)S_LEN * BD + (size_t)LAYERS * BD
                      + ((size_t)l * BATCH + b) * (3 * DDIM);
    if (*flag) {
        float* o = (float*)out;
        o[hoff] = hv;
        o[eoff + d] = cv; o[eoff + DDIM + d] = nv; o[eoff + 2 * DDIM + d] = mv;
    } else {
        unsigned short* o = (unsigned short*)out;
        o[hoff] = f2bf(hv);
        o[eoff + d]            = f2bf(cv);
        o[eoff + DDIM + d]     = f2bf(nv);
        o[eoff + 2 * DDIM + d] = f2bf(mv);
    }
}

__global__ void zero_out_k(void* __restrict__ out, const int* __restrict__ flag,
                           int out_size)
{
    const size_t i = (size_t)blockIdx.x * 256 + threadIdx.x;
    const size_t nb = (size_t)out_size * ((*flag) ? 4 : 2);
    char* o = (char*)out;
    for (size_t j = i * 4; j < (i + 1) * 4 && j < nb; j++) o[j] = 0;
}

// ---------------------------------------------------------------------------
extern "C" void kernel_launch(void* const* d_in, const int* in_sizes, int n_in,
                              void* d_out, int out_size, void* d_ws, size_t ws_size,
                              hipStream_t stream)
{
    const void* input  = d_in[0];
    const void* h0     = d_in[1];
    const void* extra0 = d_in[2];
    const void* W0     = d_in[3];
    const void* b0     = d_in[4];
    const void* r0     = d_in[5];
    const void* W1     = d_in[6];
    const void* b1     = d_in[7];
    const void* r1     = d_in[8];

    const size_t FLAG_B  = 256;
    const size_t STATE_B = (size_t)LAYERS * 4 * BD * 4;   // 512 KB
    const size_t W_B     = (size_t)NG * IDIM * 2;          // 8 MB each
    const size_t PB_B    = (size_t)4 * NG * 4;             // 64 KB
    const size_t SM_B    = (size_t)4 * NSEG * BD * 4;      // 8 MB (summaries + seg-init)
    const size_t FIXED   = FLAG_B + STATE_B + 2 * W_B + PB_B + SM_B;

    int T = 0;
    for (int cand = S_LEN; cand >= 8; cand >>= 1) {
        size_t need = FIXED
                    + (size_t)cand * BD * 2                   // Ain  (bf16)
                    + (size_t)cand * BD * 2                   // hseq (bf16)
                    + (size_t)(cand + PF) * BATCH * NG * 2;   // pre  (bf16)
        if (need <= ws_size) { T = cand; break; }
    }

    char* ws = (char*)d_ws;
    int*   flag  = (int*)ws;
    int*   rflag = flag + 1;                               // rflag[0], rflag[1]
    float* state = (float*)(ws + FLAG_B);
    __hip_bfloat16* W0b = (__hip_bfloat16*)(ws + FLAG_B + STATE_B);
    __hip_bfloat16* W1b = W0b + (size_t)NG * IDIM;
    float* pb    = (float*)(ws + FLAG_B + STATE_B + 2 * W_B);
    float* b0f = pb, *r0f = pb + NG, *b1f = pb + 2 * NG, *r1f = pb + 3 * NG;
    float* smry  = (float*)(ws + FLAG_B + STATE_B + 2 * W_B + PB_B);
    unsigned short* Ain  = (unsigned short*)(ws + FIXED);
    unsigned short* hseq = Ain + (size_t)T * BD;
    unsigned short* pre  = hseq + (size_t)T * BD;

    detect_dtype<<<dim3(1), dim3(64), 0, stream>>>(W0, flag);

    if (T == 0) {
        zero_out_k<<<dim3((out_size + 255) / 256), dim3(256), 0, stream>>>(d_out, flag, out_size);
        return;
    }

    const int WN = NG * IDIM;
    to_bf16<<<dim3(WN / 256), dim3(256), 0, stream>>>(W0, 0, flag, (unsigned short*)W0b, WN);
    to_bf16<<<dim3(WN / 256), dim3(256), 0, stream>>>(W1, 0, flag, (unsigned short*)W1b, WN);

    prep_small<<<dim3(132), dim3(256), 0, stream>>>(h0, extra0, b0, r0, b1, r1,
                                                    flag, state, pb, rflag);

    const dim3 gemmGrid(32, (T * BATCH) / 128);
    const dim3 scanGrid(BD / 64);
    const dim3 passGrid((BD * NSEG) / 256);
    const dim3 midGrid(BD / 256);
    const int  nch = S_LEN / T;
    // parallel path needs SEG = T/NSEG to be a positive multiple of PFP
    const int  useP = (T >= 256 && (T % (NSEG * PFP)) == 0) ? 1 : 0;

    for (int ch = 0; ch < nch; ch++) {
        const int t0 = ch * T;

        to_bf16<<<dim3((T * BD) / 256), dim3(256), 0, stream>>>(
            input, (size_t)t0 * BD, flag, Ain, T * BD);

        // ---- layer 0 ----
        gemm_bias<<<gemmGrid, 256, 0, stream>>>((const __hip_bfloat16*)Ain, W0b, b0f, pre, rflag + 0);
        if (useP) {
            scan_passA<<<passGrid, 256, 0, stream>>>((const unsigned int*)pre, rflag + 0, smry, T);
            scan_mid<<<midGrid, 256, 0, stream>>>(smry, rflag + 0, state, T);
            scan_passB<0><<<passGrid, 256, 0, stream>>>((const unsigned int*)pre, smry, rflag + 0,
                                                        state, hseq, (void*)0, 0, flag, T);
        }
        slstm_scan<0><<<scanGrid, 64, 0, stream>>>((const unsigned int*)pre, r0f, state,
                                                   hseq, (void*)0, 0, flag, rflag + 0, T, useP);

        // ---- layer 1 ----
        gemm_bias<<<gemmGrid, 256, 0, stream>>>((const __hip_bfloat16*)hseq, W1b, b1f, pre, rflag + 1);
        if (useP) {
            scan_passA<<<passGrid, 256, 0, stream>>>((const unsigned int*)pre, rflag + 1, smry, T);
            scan_mid<<<midGrid, 256, 0, stream>>>(smry, rflag + 1, state + 4 * BD, T);
            scan_passB<1><<<passGrid, 256, 0, stream>>>((const unsigned int*)pre, smry, rflag + 1,
                                                        state + 4 * BD, (unsigned short*)0,
                                                        d_out, (size_t)t0 * BD, flag, T);
        }
        slstm_scan<1><<<scanGrid, 64, 0, stream>>>((const unsigned int*)pre, r1f,
                                                   state + 4 * BD, (unsigned short*)0,
                                                   d_out, (size_t)t0 * BD, flag, rflag + 1, T, useP);
    }

    finalize<<<dim3(LAYERS * BD / 256), dim3(256), 0, stream>>>(state, d_out, flag);
}

// Round 8
// 630.577 us; speedup vs baseline: 1.1904x; 1.0658x over previous
//
#include <hip/hip_runtime.h>
#include <hip/hip_bf16.h>

#define S_LEN  1024
#define BATCH  16
#define IDIM   1024
#define DDIM   1024
#define NG     4096     // 4*DDIM
#define BD     16384    // BATCH*DDIM
#define LAYERS 2
#define PF     16       // seq-scan prefetch depth (pre has PF extra steps pad)
#define PFP    8        // parallel-pass prefetch depth
#define NSEG   16       // time segments for the parallel scan

typedef __attribute__((ext_vector_type(8))) short   short8;
typedef __attribute__((ext_vector_type(4))) float   floatx4;
typedef __attribute__((address_space(1))) void      as1_void;
typedef __attribute__((address_space(3))) void      as3_void;

#define L2E  1.4426950408889634f   // log2(e)
#define LN2  0.6931471805599453f

#define EXP2F(x) exp2f(x)

// RNE f32->bf16, 3 ops (NaN irrelevant here)
static __device__ __forceinline__ unsigned short f2bf(float x) {
    unsigned int u = __float_as_uint(x);
    return (unsigned short)((u + 0x7fffu + ((u >> 16) & 1u)) >> 16);
}

// ---------------------------------------------------------------------------
// Dtype detect: read W0 head AS bf16; f32 garbage -> max |v| huge.
// flag: 1 = f32 I/O, 0 = bf16 I/O.
// ---------------------------------------------------------------------------
__global__ void detect_dtype(const void* w, int* flag)
{
    const __hip_bfloat16* p = (const __hip_bfloat16*)w;
    float mx = 0.0f;
    for (int i = threadIdx.x; i < 4096; i += 64) {
        float v = __bfloat162float(p[i]);
        float a = fabsf(v);
        if (!(a == a)) a = 1e30f;
        mx = fmaxf(mx, a);
    }
#pragma unroll
    for (int o = 32; o > 0; o >>= 1)
        mx = fmaxf(mx, __shfl_down(mx, o, 64));
    if (threadIdx.x == 0) *flag = (mx > 1e3f) ? 1 : 0;
}

__global__ void to_bf16(const void* src, size_t elem_off, const int* flag,
                        unsigned short* dst, int n)
{
    const int i = blockIdx.x * 256 + threadIdx.x;
    if (i >= n) return;
    if (*flag) dst[i] = f2bf(((const float*)src)[elem_off + i]);
    else       dst[i] = ((const unsigned short*)src)[elem_off + i];
}

// ---------------------------------------------------------------------------
// Fused prep: init_state (blocks 0..127) + bias/r conversions + r==0 detect
// (blocks 128..131). r-zero detect reads the RAW r inputs (dtype via flag).
// ---------------------------------------------------------------------------
__global__ void prep_small(const void* __restrict__ h0,
                           const void* __restrict__ extra0,
                           const void* __restrict__ b0s, const void* __restrict__ r0s,
                           const void* __restrict__ b1s, const void* __restrict__ r1s,
                           const int* __restrict__ flag,
                           float* __restrict__ state,
                           float* __restrict__ pb,     // b0f,r0f,b1f,r1f (NG each)
                           int* __restrict__ rflag)
{
    const int blk = blockIdx.x;
    const int fl = *flag;

    if (blk < 128) {
        const int idx = blk * 256 + threadIdx.x;  // 0..L*BD
        const int l  = idx / BD;
        const int bd = idx % BD;
        const int b = bd >> 10, d = bd & 1023;
        float* st = state + (size_t)l * 4 * BD;
        const size_t eoff = ((size_t)l * BATCH + b) * (3 * DDIM);
        float cv, nv, mv, hv;
        if (fl) {
            const float* e = (const float*)extra0 + eoff;
            cv = e[d]; nv = e[DDIM + d]; mv = e[2 * DDIM + d];
            hv = ((const float*)h0)[(size_t)l * BD + bd];
        } else {
            const __hip_bfloat16* e = (const __hip_bfloat16*)extra0 + eoff;
            cv = __bfloat162float(e[d]);
            nv = __bfloat162float(e[DDIM + d]);
            mv = __bfloat162float(e[2 * DDIM + d]);
            hv = __bfloat162float(((const __hip_bfloat16*)h0)[(size_t)l * BD + bd]);
        }
        st[0 * BD + bd] = cv;
        st[1 * BD + bd] = nv;
        st[2 * BD + bd] = mv * L2E;   // log2 domain
        st[3 * BD + bd] = hv;
        return;
    }

    // blocks 128..131: convert one NG-vector; 129/131 also detect r==0.
    const int which = blk - 128;              // 0:b0 1:r0 2:b1 3:r1
    const void* src = (which == 0) ? b0s : (which == 1) ? r0s
                    : (which == 2) ? b1s : r1s;
    float* dst = pb + (size_t)which * NG;
    int nz = 0;
#pragma unroll
    for (int j = 0; j < NG / 256; j++) {
        const int i = j * 256 + threadIdx.x;
        float v;
        if (fl) {
            v = ((const float*)src)[i];
            nz |= (v != 0.0f);
        } else {
            const unsigned short u = ((const unsigned short*)src)[i];
            nz |= ((u & 0x7fffu) != 0);
            v = __bfloat162float(((const __hip_bfloat16*)src)[i]);
        }
        dst[i] = v;
    }
    if (which == 1 || which == 3) {
        __shared__ int s[4];
        const int w = threadIdx.x >> 6;
        const int any = __any(nz) ? 1 : 0;
        if ((threadIdx.x & 63) == 0) s[w] = any;
        __syncthreads();
        if (threadIdx.x == 0) rflag[which >> 1] = !(s[0] | s[1] | s[2] | s[3]);
    }
}

// ---------------------------------------------------------------------------
// GEMM with gate-interleaved, log2-scaled output. CHAINBLOCK-TILED layout:
//   pre[(cb*tpad + t)*64 + cl] (8B gate-packs), cb = chain>>6, cl = chain&63.
// Rationale (round-7 PMC): the old [t][chain] layout gave each scan wave a
// 512B-chunk stream at 128KB stride -> per-CU line-miss limit capped passes
// at ~2.1 TB/s at ANY occupancy (4 and 32 waves/CU identical). This layout
// makes each wave's stream 512B chunks that are ADJACENT in memory (m13-style
// sequential copy = 6.3 TB/s). Epilogue: each 16-lane quad still writes 128B
// contiguous, 128B-aligned (full lines, no RMW — round-6's failure was
// lane-scattered 8KB-apart stores, NOT this).
// 1.68e7 LDS bank conflicts accepted (round-1 A/B: fixing cost +1.7%);
// single-buffer LDS (round-5 A/B: 2-phase dbuf cost +3.5%).
// rfast=1: gate0 -> tanh(z_pre), gate3 -> sigmoid(o_pre); gates 1,2 log2-scaled.
// ---------------------------------------------------------------------------
__global__ __launch_bounds__(256, 2)
void gemm_bias(const __hip_bfloat16* __restrict__ A,
               const __hip_bfloat16* __restrict__ W,
               const float* __restrict__ bias,
               unsigned short* __restrict__ out,
               const int* __restrict__ rflag, int tpad)
{
    constexpr int K = 1024;
    __shared__ alignas(16) __hip_bfloat16 sA[128 * 32];
    __shared__ alignas(16) __hip_bfloat16 sB[128 * 32];

    const int t  = threadIdx.x;
    const int m0 = blockIdx.y * 128;
    const int nb = blockIdx.x;          // d-block: d in [nb*32, nb*32+32)
    const int lr = t & 15;
    const int q  = (t >> 4) & 3;
    const int w  = t >> 6;
    const int wm = w >> 1, wn = w & 1;
    const int sr = t >> 2;              // staging row 0..63
    const int sk = (t & 3) * 8;         // staging k-offset (elements)

    floatx4 acc[4][4] = {};

    const __hip_bfloat16* Ab = A + (size_t)(m0 + sr) * K + sk;
    const int wrow = ((sr >> 5) << 10) + nb * 32 + (sr & 31);
    const __hip_bfloat16* Wb = W + (size_t)wrow * K + sk;

    for (int k0 = 0; k0 < K; k0 += 32) {
        __syncthreads();
        __builtin_amdgcn_global_load_lds((as1_void*)(Ab + k0),            (as3_void*)&sA[sr * 32 + sk],        16, 0, 0);
        __builtin_amdgcn_global_load_lds((as1_void*)(Ab + 64 * K + k0),   (as3_void*)&sA[(sr + 64) * 32 + sk], 16, 0, 0);
        __builtin_amdgcn_global_load_lds((as1_void*)(Wb + k0),            (as3_void*)&sB[sr * 32 + sk],        16, 0, 0);
        __builtin_amdgcn_global_load_lds((as1_void*)(Wb + 2048 * K + k0), (as3_void*)&sB[(sr + 64) * 32 + sk], 16, 0, 0);
        __syncthreads();

        short8 af[4], bf[4];
#pragma unroll
        for (int i = 0; i < 4; i++)
            af[i] = *(const short8*)&sA[(wm * 64 + i * 16 + lr) * 32 + q * 8];
#pragma unroll
        for (int j = 0; j < 4; j++)   // j = gate, local d = wn*16 + lr
            bf[j] = *(const short8*)&sB[(j * 32 + wn * 16 + lr) * 32 + q * 8];
#pragma unroll
        for (int i = 0; i < 4; i++)
#pragma unroll
            for (int j = 0; j < 4; j++)
                acc[i][j] = __builtin_amdgcn_mfma_f32_16x16x32_bf16(af[i], bf[j], acc[i][j], 0, 0, 0);
    }

    // epilogue: lane owns d = nb*32 + wn*16 + lr, all 4 gates -> 8B stores.
    // chain = b*1024 + d; cb = b*16 + (nb>>1); cl = (nb&1)*32 + wn*16 + lr.
    const int d = nb * 32 + wn * 16 + lr;
    const int cl = ((nb & 1) << 5) + wn * 16 + lr;
    const int cbBase = nb >> 1;          // + b*16
    const float sc[4] = {2.0f * L2E, L2E, L2E, L2E};
    float bb[4];
#pragma unroll
    for (int g = 0; g < 4; g++) bb[g] = sc[g] * bias[g * 1024 + d];

    const int rfast = *rflag;   // uniform scalar branch

#pragma unroll
    for (int i = 0; i < 4; i++) {
#pragma unroll
        for (int reg = 0; reg < 4; reg++) {
            const int row  = m0 + wm * 64 + i * 16 + q * 4 + reg;
            const int trow = row >> 4;
            const int b    = row & 15;
            float v[4];
#pragma unroll
            for (int g = 0; g < 4; g++)
                v[g] = acc[i][g][reg] * sc[g] + bb[g];
            if (rfast) {
                // gate0 holds 2*L2E*z_pre: tanh(z) = sign*(1-e^-2|z|)/(1+e^-2|z|)
                const float zv = v[0];
                const float e2 = EXP2F(-fabsf(zv));
                v[0] = copysignf((1.0f - e2) * __builtin_amdgcn_rcpf(1.0f + e2), zv);
                // gate3 holds L2E*o_pre: sigmoid
                v[3] = __builtin_amdgcn_rcpf(1.0f + EXP2F(-v[3]));
            }
            union { unsigned short us[4]; uint2 u2; } pk;
#pragma unroll
            for (int g = 0; g < 4; g++) pk.us[g] = f2bf(v[g]);
            const int cb = b * 16 + cbBase;
            *(uint2*)(out + (((size_t)cb * tpad + trow) * 64 + cl) * 4) = pk.u2;
        }
    }
}

// ---------------------------------------------------------------------------
// Parallel scan over time (rfast only): the r==0 recurrence is associative.
// Chainblock-tiled pre: wave = one chainblock; per step it reads 512B
// contiguous, successive steps ADJACENT -> sequential stream per wave.
// NSEG=16 -> 1024 blocks = 16 waves/CU; each wave streams SEG*512B = 32KB.
// passA: per (chain, segment) summary (A=sum f, bmax=A+mu, Bhat, Nhat).
// mid:   per chain, compose NSEG summaries sequentially (exact); overwrites
//        smry slots 0..2 with each segment's incoming (c, n, m2).
// passB: per (chain, segment) exact sequential walk emitting h.
// ---------------------------------------------------------------------------
__global__ void scan_passA(const unsigned int* __restrict__ pre,
                           const int* __restrict__ rflag,
                           float* __restrict__ smry, int T, int tpad)
{
    if (!*rflag) return;
    const int gid = blockIdx.x * 256 + threadIdx.x;   // 0..BD*NSEG
    const int chain = gid & (BD - 1);
    const int seg = gid >> 14;
    const int SEG = T / NSEG;
    const int cb = chain >> 6, cl = chain & 63;

    const uint2* p = (const uint2*)pre
                   + ((size_t)cb * tpad + seg * SEG) * 64 + cl;

    float al = 0.0f, mu = -3e38f, Bh = 0.0f, Nh = 0.0f;

    unsigned int k0[PFP], k1[PFP];
#pragma unroll
    for (int u = 0; u < PFP; u++) {
        const uint2 v = p[(size_t)u * 64];
        k0[u] = v.x; k1[u] = v.y;
    }

    for (int t = 0; t < SEG; t += PFP) {
#pragma unroll
        for (int u = 0; u < PFP; u++) {
            const float zt = __uint_as_float(k0[u] << 16);        // tanh(z)
            const float i2 = __uint_as_float(k0[u] & 0xffff0000u);
            const float f2 = __uint_as_float(k1[u] << 16);

            const uint2 nv = p[(size_t)(t + u + PFP) * 64];
            k0[u] = nv.x; k1[u] = nv.y;

            al += f2;
            const float e  = i2 - al;
            const float mn = fmaxf(mu, e);
            const float s  = EXP2F(mu - mn);
            const float ww = EXP2F(e - mn);
            Bh = fmaf(Bh, s, ww * zt);
            Nh = fmaf(Nh, s, ww);
            mu = mn;
        }
    }

    smry[0 * NSEG * BD + seg * BD + chain] = al;
    smry[1 * NSEG * BD + seg * BD + chain] = al + mu;   // bmax
    smry[2 * NSEG * BD + seg * BD + chain] = Bh;
    smry[3 * NSEG * BD + seg * BD + chain] = Nh;
}

__global__ void scan_mid(float* __restrict__ smry,
                         const int* __restrict__ rflag,
                         const float* __restrict__ state, int T)
{
    if (!*rflag) return;
    const int idx = blockIdx.x * 256 + threadIdx.x;    // 0..BD
    float c  = state[0 * BD + idx];
    float n  = state[1 * BD + idx];
    float m2 = state[2 * BD + idx];
#pragma unroll
    for (int s = 0; s < NSEG; s++) {
        const float A    = smry[0 * NSEG * BD + s * BD + idx];
        const float bmax = smry[1 * NSEG * BD + s * BD + idx];
        const float Bh   = smry[2 * NSEG * BD + s * BD + idx];
        const float Nh   = smry[3 * NSEG * BD + s * BD + idx];
        // overwrite consumed summary slots with this segment's INCOMING state
        smry[0 * NSEG * BD + s * BD + idx] = c;
        smry[1 * NSEG * BD + s * BD + idx] = n;
        smry[2 * NSEG * BD + s * BD + idx] = m2;
        const float mn = fmaxf(m2 + A, bmax);
        const float sc = EXP2F(m2 + A - mn);
        const float w  = EXP2F(bmax - mn);
        c  = fmaf(sc, c, w * Bh);
        n  = fmaf(sc, n, w * Nh);
        m2 = mn;
    }
}

template<int MODE>
__global__ void scan_passB(const unsigned int* __restrict__ pre,
                           const float* __restrict__ smry,   // seg-init in slots 0..2
                           const int* __restrict__ rflag,
                           float* __restrict__ state,
                           unsigned short* __restrict__ hseq,
                           void* __restrict__ gout, size_t gout_eoff,
                           const int* __restrict__ flag, int T, int tpad)
{
    if (!*rflag) return;
    const int gid = blockIdx.x * 256 + threadIdx.x;
    const int chain = gid & (BD - 1);
    const int seg = gid >> 14;
    const int SEG = T / NSEG;
    const int t0s = seg * SEG;
    const int cb = chain >> 6, cl = chain & 63;
    const int fl = *flag;

    float c  = smry[0 * NSEG * BD + seg * BD + chain];
    float n  = smry[1 * NSEG * BD + seg * BD + chain];
    float m2 = smry[2 * NSEG * BD + seg * BD + chain];

    const uint2* p = (const uint2*)pre
                   + ((size_t)cb * tpad + t0s) * 64 + cl;

    unsigned short* hb = hseq + chain + (size_t)t0s * BD;
    float*          fo = (float*)gout + gout_eoff + chain + (size_t)t0s * BD;
    unsigned short* bo = (unsigned short*)gout + gout_eoff + chain + (size_t)t0s * BD;

    float h = 0.0f;
    unsigned int k0[PFP], k1[PFP];
#pragma unroll
    for (int u = 0; u < PFP; u++) {
        const uint2 v = p[(size_t)u * 64];
        k0[u] = v.x; k1[u] = v.y;
    }

    for (int t = 0; t < SEG; t += PFP) {
#pragma unroll
        for (int u = 0; u < PFP; u++) {
            const float zt = __uint_as_float(k0[u] << 16);        // tanh(z)
            const float i2 = __uint_as_float(k0[u] & 0xffff0000u);
            const float f2 = __uint_as_float(k1[u] << 16);
            const float ot = __uint_as_float(k1[u] & 0xffff0000u); // sigmoid(o)

            const uint2 nv = p[(size_t)(t + u + PFP) * 64];
            k0[u] = nv.x; k1[u] = nv.y;

            const float fm = f2 + m2;
            const float mn = fmaxf(fm, i2);
            const float ft = EXP2F(fm - mn);
            const float it = EXP2F(i2 - mn);

            c  = fmaf(ft, c, it * zt);
            n  = fmaf(ft, n, it);
            m2 = mn;
            h  = ot * c * __builtin_amdgcn_rcpf(fabsf(n) + 1e-6f);

            const size_t toff = (size_t)(t + u) * BD;
            if (MODE == 0)      hb[toff] = f2bf(h);
            else if (fl)        fo[toff] = h;
            else                bo[toff] = f2bf(h);
        }
    }

    if (seg == NSEG - 1) {
        state[0 * BD + chain] = c;
        state[1 * BD + chain] = n;
        state[2 * BD + chain] = m2;
        state[3 * BD + chain] = h;
    }
}

// ---------------------------------------------------------------------------
// Sequential sLSTM scan — general fallback (handles r != 0). When pgate=1 and
// rflag=1 the parallel path owns this layer and this kernel early-exits.
// Chainblock-tiled pre addressing (sequential per-wave stream here too).
// ---------------------------------------------------------------------------
template<int MODE>
__global__ void slstm_scan(const unsigned int* __restrict__ pre,
                           const float* __restrict__ r,
                           float* __restrict__ state,
                           unsigned short* __restrict__ hseq,
                           void* __restrict__ gout, size_t gout_eoff,
                           const int* __restrict__ flag,
                           const int* __restrict__ rflag, int T, int tpad,
                           int pgate)
{
    const int rfast = *rflag;
    if (pgate && rfast) return;

    const int idx = blockIdx.x * 64 + threadIdx.x;  // 0..BD (chain)
    const int d = idx & 1023;
    const int cb = idx >> 6, cl = idx & 63;
    const int fl = *flag;

    const float rz = r[d]            * (2.0f * L2E);
    const float ri = r[DDIM + d]     * L2E;
    const float rf = r[2 * DDIM + d] * L2E;
    const float ro = r[3 * DDIM + d] * L2E;

    float c  = state[0 * BD + idx];
    float n  = state[1 * BD + idx];
    float m2 = state[2 * BD + idx];   // log2 domain
    float h  = state[3 * BD + idx];

    const uint2* p = (const uint2*)pre + (size_t)cb * tpad * 64 + cl;

    unsigned short* hb = hseq + idx;
    float*          fo = (float*)gout + gout_eoff + idx;
    unsigned short* bo = (unsigned short*)gout + gout_eoff + idx;

    unsigned int k0[PF], k1[PF];
#pragma unroll
    for (int u = 0; u < PF; u++) {
        const uint2 v = p[(size_t)u * 64];
        k0[u] = v.x; k1[u] = v.y;
    }

    if (rfast) {
        for (int t8 = 0; t8 < T; t8 += PF) {
#pragma unroll
            for (int u = 0; u < PF; u++) {
                const float zt = __uint_as_float(k0[u] << 16);
                const float i2 = __uint_as_float(k0[u] & 0xffff0000u);
                const float f2 = __uint_as_float(k1[u] << 16);
                const float ot = __uint_as_float(k1[u] & 0xffff0000u);

                const uint2 nv = p[(size_t)(t8 + u + PF) * 64];
                k0[u] = nv.x; k1[u] = nv.y;

                const float fm = f2 + m2;
                const float mn = fmaxf(fm, i2);
                const float ft = EXP2F(fm - mn);
                const float it = EXP2F(i2 - mn);

                c  = fmaf(ft, c, it * zt);
                n  = fmaf(ft, n, it);
                m2 = mn;
                h  = ot * c * __builtin_amdgcn_rcpf(fabsf(n) + 1e-6f);

                const size_t toff = (size_t)(t8 + u) * BD;
                if (MODE == 0)      hb[toff] = f2bf(h);
                else if (fl)        fo[toff] = h;
                else                bo[toff] = f2bf(h);
            }
        }
    } else {
        for (int t8 = 0; t8 < T; t8 += PF) {
#pragma unroll
            for (int u = 0; u < PF; u++) {
                float z2 = __uint_as_float(k0[u] << 16);
                float i2 = __uint_as_float(k0[u] & 0xffff0000u);
                float f2 = __uint_as_float(k1[u] << 16);
                float o2 = __uint_as_float(k1[u] & 0xffff0000u);

                const uint2 nv = p[(size_t)(t8 + u + PF) * 64];
                k0[u] = nv.x; k1[u] = nv.y;

                z2 = fmaf(rz, h, z2);
                i2 = fmaf(ri, h, i2);
                f2 = fmaf(rf, h, f2);
                o2 = fmaf(ro, h, o2);

                const float fm = f2 + m2;
                const float mn = fmaxf(fm, i2);
                const float ft = EXP2F(fm - mn);   // <= 1
                const float it = EXP2F(i2 - mn);   // <= 1

                const float e2 = EXP2F(-fabsf(z2));
                const float zt = copysignf((1.0f - e2) * __builtin_amdgcn_rcpf(1.0f + e2), z2);
                const float ot = __builtin_amdgcn_rcpf(1.0f + EXP2F(-o2));

                c  = ft * c + it * zt;
                n  = ft * n + it;
                m2 = mn;
                h  = ot * c * __builtin_amdgcn_rcpf(fabsf(n) + 1e-6f);

                const size_t toff = (size_t)(t8 + u) * BD;
                if (MODE == 0)      hb[toff] = f2bf(h);
                else if (fl)        fo[toff] = h;
                else                bo[toff] = f2bf(h);
            }
        }
    }

    state[0 * BD + idx] = c;
    state[1 * BD + idx] = n;
    state[2 * BD + idx] = m2;
    state[3 * BD + idx] = h;
}

// ---------------------------------------------------------------------------
__global__ void finalize(const float* __restrict__ state,
                         void* __restrict__ out,
                         const int* __restrict__ flag)
{
    const int idx = blockIdx.x * 256 + threadIdx.x;  // 0..L*BD
    const int l  = idx / BD;
    const int bd = idx % BD;
    const int b = bd >> 10, d = bd & 1023;
    const float* st = state + (size_t)l * 4 * BD;
    const float cv = st[0 * BD + bd], nv = st[1 * BD + bd];
    const float mv = st[2 * BD + bd] * LN2;          // back from log2 domain
    const float hv = st[3 * BD + bd];

    const size_t hoff = (size_t)S_LEN * BD + idx;
    const size_t eoff = (size_t)S_LEN * BD + (size_t)LAYERS * BD
                      + ((size_t)l * BATCH + b) * (3 * DDIM);
    if (*flag) {
        float* o = (float*)out;
        o[hoff] = hv;
        o[eoff + d] = cv; o[eoff + DDIM + d] = nv; o[eoff + 2 * DDIM + d] = mv;
    } else {
        unsigned short* o = (unsigned short*)out;
        o[hoff] = f2bf(hv);
        o[eoff + d]            = f2bf(cv);
        o[eoff + DDIM + d]     = f2bf(nv);
        o[eoff + 2 * DDIM + d] = f2bf(mv);
    }
}

__global__ void zero_out_k(void* __restrict__ out, const int* __restrict__ flag,
                           int out_size)
{
    const size_t i = (size_t)blockIdx.x * 256 + threadIdx.x;
    const size_t nb = (size_t)out_size * ((*flag) ? 4 : 2);
    char* o = (char*)out;
    for (size_t j = i * 4; j < (i + 1) * 4 && j < nb; j++) o[j] = 0;
}

// ---------------------------------------------------------------------------
extern "C" void kernel_launch(void* const* d_in, const int* in_sizes, int n_in,
                              void* d_out, int out_size, void* d_ws, size_t ws_size,
                              hipStream_t stream)
{
    const void* input  = d_in[0];
    const void* h0     = d_in[1];
    const void* extra0 = d_in[2];
    const void* W0     = d_in[3];
    const void* b0     = d_in[4];
    const void* r0     = d_in[5];
    const void* W1     = d_in[6];
    const void* b1     = d_in[7];
    const void* r1     = d_in[8];

    const size_t FLAG_B  = 256;
    const size_t STATE_B = (size_t)LAYERS * 4 * BD * 4;   // 512 KB
    const size_t W_B     = (size_t)NG * IDIM * 2;          // 8 MB each
    const size_t PB_B    = (size_t)4 * NG * 4;             // 64 KB
    const size_t SM_B    = (size_t)4 * NSEG * BD * 4;      // 4 MB (summaries + seg-init)
    const size_t FIXED   = FLAG_B + STATE_B + 2 * W_B + PB_B + SM_B;

    int T = 0;
    for (int cand = S_LEN; cand >= 8; cand >>= 1) {
        size_t need = FIXED
                    + (size_t)cand * BD * 2                   // Ain  (bf16)
                    + (size_t)cand * BD * 2                   // hseq (bf16)
                    + (size_t)(cand + PF) * BD * 8;           // pre (chainblock-tiled)
        if (need <= ws_size) { T = cand; break; }
    }

    char* ws = (char*)d_ws;
    int*   flag  = (int*)ws;
    int*   rflag = flag + 1;                               // rflag[0], rflag[1]
    float* state = (float*)(ws + FLAG_B);
    __hip_bfloat16* W0b = (__hip_bfloat16*)(ws + FLAG_B + STATE_B);
    __hip_bfloat16* W1b = W0b + (size_t)NG * IDIM;
    float* pb    = (float*)(ws + FLAG_B + STATE_B + 2 * W_B);
    float* b0f = pb, *r0f = pb + NG, *b1f = pb + 2 * NG, *r1f = pb + 3 * NG;
    float* smry  = (float*)(ws + FLAG_B + STATE_B + 2 * W_B + PB_B);
    unsigned short* Ain  = (unsigned short*)(ws + FIXED);
    unsigned short* hseq = Ain + (size_t)T * BD;
    unsigned short* pre  = hseq + (size_t)T * BD;

    detect_dtype<<<dim3(1), dim3(64), 0, stream>>>(W0, flag);

    if (T == 0) {
        zero_out_k<<<dim3((out_size + 255) / 256), dim3(256), 0, stream>>>(d_out, flag, out_size);
        return;
    }

    const int WN = NG * IDIM;
    to_bf16<<<dim3(WN / 256), dim3(256), 0, stream>>>(W0, 0, flag, (unsigned short*)W0b, WN);
    to_bf16<<<dim3(WN / 256), dim3(256), 0, stream>>>(W1, 0, flag, (unsigned short*)W1b, WN);

    prep_small<<<dim3(132), dim3(256), 0, stream>>>(h0, extra0, b0, r0, b1, r1,
                                                    flag, state, pb, rflag);

    const int  tpad = T + PF;
    const dim3 gemmGrid(32, (T * BATCH) / 128);
    const dim3 scanGrid(BD / 64);
    const dim3 passGrid((BD * NSEG) / 256);
    const dim3 midGrid(BD / 256);
    const int  nch = S_LEN / T;
    // parallel path needs SEG = T/NSEG to be a positive multiple of PFP
    const int  useP = (T >= 256 && (T % (NSEG * PFP)) == 0) ? 1 : 0;

    for (int ch = 0; ch < nch; ch++) {
        const int t0 = ch * T;

        to_bf16<<<dim3((T * BD) / 256), dim3(256), 0, stream>>>(
            input, (size_t)t0 * BD, flag, Ain, T * BD);

        // ---- layer 0 ----
        gemm_bias<<<gemmGrid, 256, 0, stream>>>((const __hip_bfloat16*)Ain, W0b, b0f, pre, rflag + 0, tpad);
        if (useP) {
            scan_passA<<<passGrid, 256, 0, stream>>>((const unsigned int*)pre, rflag + 0, smry, T, tpad);
            scan_mid<<<midGrid, 256, 0, stream>>>(smry, rflag + 0, state, T);
            scan_passB<0><<<passGrid, 256, 0, stream>>>((const unsigned int*)pre, smry, rflag + 0,
                                                        state, hseq, (void*)0, 0, flag, T, tpad);
        }
        slstm_scan<0><<<scanGrid, 64, 0, stream>>>((const unsigned int*)pre, r0f, state,
                                                   hseq, (void*)0, 0, flag, rflag + 0, T, tpad, useP);

        // ---- layer 1 ----
        gemm_bias<<<gemmGrid, 256, 0, stream>>>((const __hip_bfloat16*)hseq, W1b, b1f, pre, rflag + 1, tpad);
        if (useP) {
            scan_passA<<<passGrid, 256, 0, stream>>>((const unsigned int*)pre, rflag + 1, smry, T, tpad);
            scan_mid<<<midGrid, 256, 0, stream>>>(smry, rflag + 1, state + 4 * BD, T);
            scan_passB<1><<<passGrid, 256, 0, stream>>>((const unsigned int*)pre, smry, rflag + 1,
                                                        state + 4 * BD, (unsigned short*)0,
                                                        d_out, (size_t)t0 * BD, flag, T, tpad);
        }
        slstm_scan<1><<<scanGrid, 64, 0, stream>>>((const unsigned int*)pre, r1f,
                                                   state + 4 * BD, (unsigned short*)0,
                                                   d_out, (size_t)t0 * BD, flag, rflag + 1, T, tpad, useP);
    }

    finalize<<<dim3(LAYERS * BD / 256), dim3(256), 0, stream>>>(state, d_out, flag);
}

// Round 9
// 594.768 us; speedup vs baseline: 1.2621x; 1.0602x over previous
//
#include <hip/hip_runtime.h>
#include <hip/hip_bf16.h>

#define S_LEN  1024
#define BATCH  16
#define IDIM   1024
#define DDIM   1024
#define NG     4096     // 4*DDIM
#define BD     16384    // BATCH*DDIM
#define LAYERS 2
#define PF     16       // seq-scan prefetch depth (pre has PF extra steps pad)
#define PFP    8        // parallel-pass prefetch depth
#define NSEG   16       // time segments for the parallel scan

typedef __attribute__((ext_vector_type(8))) short   short8;
typedef __attribute__((ext_vector_type(4))) float   floatx4;
typedef __attribute__((address_space(1))) void      as1_void;
typedef __attribute__((address_space(3))) void      as3_void;

#define L2E  1.4426950408889634f   // log2(e)
#define LN2  0.6931471805599453f

#define EXP2F(x) exp2f(x)

// RNE f32->bf16, 3 ops (NaN irrelevant here)
static __device__ __forceinline__ unsigned short f2bf(float x) {
    unsigned int u = __float_as_uint(x);
    return (unsigned short)((u + 0x7fffu + ((u >> 16) & 1u)) >> 16);
}

// ---------------------------------------------------------------------------
// Dtype detect: read W0 head AS bf16; f32 garbage -> max |v| huge.
// flag: 1 = f32 I/O, 0 = bf16 I/O.
// ---------------------------------------------------------------------------
__global__ void detect_dtype(const void* w, int* flag)
{
    const __hip_bfloat16* p = (const __hip_bfloat16*)w;
    float mx = 0.0f;
    for (int i = threadIdx.x; i < 4096; i += 64) {
        float v = __bfloat162float(p[i]);
        float a = fabsf(v);
        if (!(a == a)) a = 1e30f;
        mx = fmaxf(mx, a);
    }
#pragma unroll
    for (int o = 32; o > 0; o >>= 1)
        mx = fmaxf(mx, __shfl_down(mx, o, 64));
    if (threadIdx.x == 0) *flag = (mx > 1e3f) ? 1 : 0;
}

__global__ void to_bf16(const void* src, size_t elem_off, const int* flag,
                        unsigned short* dst, int n)
{
    const int i = blockIdx.x * 256 + threadIdx.x;
    if (i >= n) return;
    if (*flag) dst[i] = f2bf(((const float*)src)[elem_off + i]);
    else       dst[i] = ((const unsigned short*)src)[elem_off + i];
}

// ---------------------------------------------------------------------------
// Fused prep: init_state (blocks 0..127) + bias/r conversions + r==0 detect
// (blocks 128..131). r-zero detect reads the RAW r inputs (dtype via flag).
// ---------------------------------------------------------------------------
__global__ void prep_small(const void* __restrict__ h0,
                           const void* __restrict__ extra0,
                           const void* __restrict__ b0s, const void* __restrict__ r0s,
                           const void* __restrict__ b1s, const void* __restrict__ r1s,
                           const int* __restrict__ flag,
                           float* __restrict__ state,
                           float* __restrict__ pb,     // b0f,r0f,b1f,r1f (NG each)
                           int* __restrict__ rflag)
{
    const int blk = blockIdx.x;
    const int fl = *flag;

    if (blk < 128) {
        const int idx = blk * 256 + threadIdx.x;  // 0..L*BD
        const int l  = idx / BD;
        const int bd = idx % BD;
        const int b = bd >> 10, d = bd & 1023;
        float* st = state + (size_t)l * 4 * BD;
        const size_t eoff = ((size_t)l * BATCH + b) * (3 * DDIM);
        float cv, nv, mv, hv;
        if (fl) {
            const float* e = (const float*)extra0 + eoff;
            cv = e[d]; nv = e[DDIM + d]; mv = e[2 * DDIM + d];
            hv = ((const float*)h0)[(size_t)l * BD + bd];
        } else {
            const __hip_bfloat16* e = (const __hip_bfloat16*)extra0 + eoff;
            cv = __bfloat162float(e[d]);
            nv = __bfloat162float(e[DDIM + d]);
            mv = __bfloat162float(e[2 * DDIM + d]);
            hv = __bfloat162float(((const __hip_bfloat16*)h0)[(size_t)l * BD + bd]);
        }
        st[0 * BD + bd] = cv;
        st[1 * BD + bd] = nv;
        st[2 * BD + bd] = mv * L2E;   // log2 domain
        st[3 * BD + bd] = hv;
        return;
    }

    // blocks 128..131: convert one NG-vector; 129/131 also detect r==0.
    const int which = blk - 128;              // 0:b0 1:r0 2:b1 3:r1
    const void* src = (which == 0) ? b0s : (which == 1) ? r0s
                    : (which == 2) ? b1s : r1s;
    float* dst = pb + (size_t)which * NG;
    int nz = 0;
#pragma unroll
    for (int j = 0; j < NG / 256; j++) {
        const int i = j * 256 + threadIdx.x;
        float v;
        if (fl) {
            v = ((const float*)src)[i];
            nz |= (v != 0.0f);
        } else {
            const unsigned short u = ((const unsigned short*)src)[i];
            nz |= ((u & 0x7fffu) != 0);
            v = __bfloat162float(((const __hip_bfloat16*)src)[i]);
        }
        dst[i] = v;
    }
    if (which == 1 || which == 3) {
        __shared__ int s[4];
        const int w = threadIdx.x >> 6;
        const int any = __any(nz) ? 1 : 0;
        if ((threadIdx.x & 63) == 0) s[w] = any;
        __syncthreads();
        if (threadIdx.x == 0) rflag[which >> 1] = !(s[0] | s[1] | s[2] | s[3]);
    }
}

// ---------------------------------------------------------------------------
// GEMM, 8-phase-style pipelined (T3+T4+T5 per the catalog; round-1/5 grafts
// onto the 2-barrier loop failed exactly as the regime-gate predicts).
// Tile 256x256 (BM=256 M-rows x [64 d x 4 gates]), BK=32, 512 threads = 8
// waves (2M x 4N). Per wave: 128 rows x 64 cols -> acc[8][4] f32x4.
// LDS: 3-deep buffers (96KB), stage lead 2 tiles; per phase: 12 ds_read ->
// stage tile k+2 (4 global_load_lds) -> lgkmcnt(0) (cross-wave buf safety) ->
// COUNTED vmcnt(4) (never 0 in loop; tail drains 0) -> barrier -> setprio(1)
// + 32 MFMA + setprio(0). K-accumulation order identical to prior kernel ->
// bitwise-identical results.
// LDS chunk-XOR swizzle (round-1-verified): source qd^((row>>1)&3), read
// q^((lr>>1)&3) -> frag reads spread over all 8 bank-quads (conflict-free).
// Output: chainblock-tiled pre (r8): pre[(cb*tpad+t)*64+cl] 8B gate-packs.
// rfast=1: gate0 -> tanh, gate3 -> sigmoid; gates 1,2 log2-scaled.
// ---------------------------------------------------------------------------
__global__ __launch_bounds__(512, 2)
void gemm_bias(const __hip_bfloat16* __restrict__ A,
               const __hip_bfloat16* __restrict__ W,
               const float* __restrict__ bias,
               unsigned short* __restrict__ out,
               const int* __restrict__ rflag, int tpad)
{
    __shared__ alignas(16) __hip_bfloat16 sA[3][256 * 32];
    __shared__ alignas(16) __hip_bfloat16 sB[3][256 * 32];

    const int t    = threadIdx.x;
    const int m0   = blockIdx.y * 256;
    const int nb   = blockIdx.x;            // 64-wide d-block
    const int lane = t & 63;
    const int lr   = lane & 15;
    const int q    = lane >> 4;             // 0..3
    const int w    = t >> 6;
    const int wm   = w >> 2, wn = w & 3;    // 2M x 4N waves

    // ---- staging precompute (thread t stages 16B x2 per operand per tile) --
    const int srow = t >> 2;                // 0..127 (j adds 128)
    const int qd   = t & 3;
    const int qs   = qd ^ ((srow >> 1) & 3);  // source chunk pre-swizzle
    const __hip_bfloat16* Abase = A + (size_t)(m0 + srow) * 1024 + qs * 8;
    const int r1   = 128 + srow;
    const int wr0  = (srow >> 6) * 1024 + nb * 64 + (srow & 63);
    const int wr1  = (r1 >> 6) * 1024 + nb * 64 + (r1 & 63);
    const __hip_bfloat16* Wb0 = W + (size_t)wr0 * 1024 + qs * 8;
    const __hip_bfloat16* Wb1 = W + (size_t)wr1 * 1024 + qs * 8;

    const int rc = q ^ ((lr >> 1) & 3);     // swizzled read chunk

    floatx4 acc[8][4] = {};

#define STAGE(bi, kk) do {                                                                                   \
    __builtin_amdgcn_global_load_lds((as1_void*)(Abase + (kk)),              (as3_void*)&sA[bi][t * 8],        16, 0, 0); \
    __builtin_amdgcn_global_load_lds((as1_void*)(Abase + 128 * 1024 + (kk)), (as3_void*)&sA[bi][4096 + t * 8], 16, 0, 0); \
    __builtin_amdgcn_global_load_lds((as1_void*)(Wb0 + (kk)),                (as3_void*)&sB[bi][t * 8],        16, 0, 0); \
    __builtin_amdgcn_global_load_lds((as1_void*)(Wb1 + (kk)),                (as3_void*)&sB[bi][4096 + t * 8], 16, 0, 0); \
} while (0)

    // prologue: prefetch tiles 0,1 (lead 2)
    STAGE(0, 0);
    STAGE(1, 32);
    asm volatile("s_waitcnt vmcnt(4)" ::: "memory");  // tile 0 resident
    __builtin_amdgcn_s_barrier();

    for (int kt = 0; kt < 32; ++kt) {
        const int cur = kt % 3;
        const __hip_bfloat16* cA = sA[cur];
        const __hip_bfloat16* cB = sB[cur];

        short8 af[8], bf[4];
#pragma unroll
        for (int i = 0; i < 8; i++)
            af[i] = *(const short8*)&cA[(wm * 128 + i * 16 + lr) * 32 + rc * 8];
#pragma unroll
        for (int g = 0; g < 4; g++)
            bf[g] = *(const short8*)&cB[(g * 64 + wn * 16 + lr) * 32 + rc * 8];

        if (kt < 30) {
            const int stg = (kt + 2) % 3;
            STAGE(stg, (kt + 2) * 32);
        }

        // own ds_reads done before barrier (cross-wave buf-reuse safety)
        asm volatile("s_waitcnt lgkmcnt(0)" ::: "memory");
        if (kt < 30)      asm volatile("s_waitcnt vmcnt(4)" ::: "memory");
        else if (kt == 30) asm volatile("s_waitcnt vmcnt(0)" ::: "memory");
        __builtin_amdgcn_s_barrier();

        __builtin_amdgcn_s_setprio(1);
#pragma unroll
        for (int i = 0; i < 8; i++)
#pragma unroll
            for (int g = 0; g < 4; g++)
                acc[i][g] = __builtin_amdgcn_mfma_f32_16x16x32_bf16(af[i], bf[g], acc[i][g], 0, 0, 0);
        __builtin_amdgcn_s_setprio(0);
    }
#undef STAGE

    // epilogue: lane owns d = nb*64 + wn*16 + lr, all 4 gates -> 8B stores.
    // chain = b*1024 + d; cb = b*16 + nb (d>>6 == nb); cl = wn*16 + lr.
    const int d  = nb * 64 + wn * 16 + lr;
    const int cl = wn * 16 + lr;
    const float sc[4] = {2.0f * L2E, L2E, L2E, L2E};
    float bb[4];
#pragma unroll
    for (int g = 0; g < 4; g++) bb[g] = sc[g] * bias[g * 1024 + d];

    const int rfast = *rflag;   // uniform scalar branch

#pragma unroll
    for (int i = 0; i < 8; i++) {
#pragma unroll
        for (int reg = 0; reg < 4; reg++) {
            const int row  = m0 + wm * 128 + i * 16 + q * 4 + reg;
            const int trow = row >> 4;
            const int b    = row & 15;
            float v[4];
#pragma unroll
            for (int g = 0; g < 4; g++)
                v[g] = acc[i][g][reg] * sc[g] + bb[g];
            if (rfast) {
                // gate0 holds 2*L2E*z_pre: tanh(z) = sign*(1-e^-2|z|)/(1+e^-2|z|)
                const float zv = v[0];
                const float e2 = EXP2F(-fabsf(zv));
                v[0] = copysignf((1.0f - e2) * __builtin_amdgcn_rcpf(1.0f + e2), zv);
                // gate3 holds L2E*o_pre: sigmoid
                v[3] = __builtin_amdgcn_rcpf(1.0f + EXP2F(-v[3]));
            }
            union { unsigned short us[4]; uint2 u2; } pk;
#pragma unroll
            for (int g = 0; g < 4; g++) pk.us[g] = f2bf(v[g]);
            const int cb = b * 16 + nb;
            *(uint2*)(out + (((size_t)cb * tpad + trow) * 64 + cl) * 4) = pk.u2;
        }
    }
}

// ---------------------------------------------------------------------------
// Parallel scan over time (rfast only): the r==0 recurrence is associative.
// Chainblock-tiled pre: wave = one chainblock; per step it reads 512B
// contiguous, successive steps ADJACENT -> sequential stream per wave.
// NSEG=16 -> 1024 blocks = 16 waves/CU.
// ---------------------------------------------------------------------------
__global__ void scan_passA(const unsigned int* __restrict__ pre,
                           const int* __restrict__ rflag,
                           float* __restrict__ smry, int T, int tpad)
{
    if (!*rflag) return;
    const int gid = blockIdx.x * 256 + threadIdx.x;   // 0..BD*NSEG
    const int chain = gid & (BD - 1);
    const int seg = gid >> 14;
    const int SEG = T / NSEG;
    const int cb = chain >> 6, cl = chain & 63;

    const uint2* p = (const uint2*)pre
                   + ((size_t)cb * tpad + seg * SEG) * 64 + cl;

    float al = 0.0f, mu = -3e38f, Bh = 0.0f, Nh = 0.0f;

    unsigned int k0[PFP], k1[PFP];
#pragma unroll
    for (int u = 0; u < PFP; u++) {
        const uint2 v = p[(size_t)u * 64];
        k0[u] = v.x; k1[u] = v.y;
    }

    for (int t = 0; t < SEG; t += PFP) {
#pragma unroll
        for (int u = 0; u < PFP; u++) {
            const float zt = __uint_as_float(k0[u] << 16);        // tanh(z)
            const float i2 = __uint_as_float(k0[u] & 0xffff0000u);
            const float f2 = __uint_as_float(k1[u] << 16);

            const uint2 nv = p[(size_t)(t + u + PFP) * 64];
            k0[u] = nv.x; k1[u] = nv.y;

            al += f2;
            const float e  = i2 - al;
            const float mn = fmaxf(mu, e);
            const float s  = EXP2F(mu - mn);
            const float ww = EXP2F(e - mn);
            Bh = fmaf(Bh, s, ww * zt);
            Nh = fmaf(Nh, s, ww);
            mu = mn;
        }
    }

    smry[0 * NSEG * BD + seg * BD + chain] = al;
    smry[1 * NSEG * BD + seg * BD + chain] = al + mu;   // bmax
    smry[2 * NSEG * BD + seg * BD + chain] = Bh;
    smry[3 * NSEG * BD + seg * BD + chain] = Nh;
}

__global__ void scan_mid(float* __restrict__ smry,
                         const int* __restrict__ rflag,
                         const float* __restrict__ state, int T)
{
    if (!*rflag) return;
    const int idx = blockIdx.x * 256 + threadIdx.x;    // 0..BD
    float c  = state[0 * BD + idx];
    float n  = state[1 * BD + idx];
    float m2 = state[2 * BD + idx];
#pragma unroll
    for (int s = 0; s < NSEG; s++) {
        const float A    = smry[0 * NSEG * BD + s * BD + idx];
        const float bmax = smry[1 * NSEG * BD + s * BD + idx];
        const float Bh   = smry[2 * NSEG * BD + s * BD + idx];
        const float Nh   = smry[3 * NSEG * BD + s * BD + idx];
        // overwrite consumed summary slots with this segment's INCOMING state
        smry[0 * NSEG * BD + s * BD + idx] = c;
        smry[1 * NSEG * BD + s * BD + idx] = n;
        smry[2 * NSEG * BD + s * BD + idx] = m2;
        const float mn = fmaxf(m2 + A, bmax);
        const float sc = EXP2F(m2 + A - mn);
        const float w  = EXP2F(bmax - mn);
        c  = fmaf(sc, c, w * Bh);
        n  = fmaf(sc, n, w * Nh);
        m2 = mn;
    }
}

template<int MODE>
__global__ void scan_passB(const unsigned int* __restrict__ pre,
                           const float* __restrict__ smry,   // seg-init in slots 0..2
                           const int* __restrict__ rflag,
                           float* __restrict__ state,
                           unsigned short* __restrict__ hseq,
                           void* __restrict__ gout, size_t gout_eoff,
                           const int* __restrict__ flag, int T, int tpad)
{
    if (!*rflag) return;
    const int gid = blockIdx.x * 256 + threadIdx.x;
    const int chain = gid & (BD - 1);
    const int seg = gid >> 14;
    const int SEG = T / NSEG;
    const int t0s = seg * SEG;
    const int cb = chain >> 6, cl = chain & 63;
    const int fl = *flag;

    float c  = smry[0 * NSEG * BD + seg * BD + chain];
    float n  = smry[1 * NSEG * BD + seg * BD + chain];
    float m2 = smry[2 * NSEG * BD + seg * BD + chain];

    const uint2* p = (const uint2*)pre
                   + ((size_t)cb * tpad + t0s) * 64 + cl;

    unsigned short* hb = hseq + chain + (size_t)t0s * BD;
    float*          fo = (float*)gout + gout_eoff + chain + (size_t)t0s * BD;
    unsigned short* bo = (unsigned short*)gout + gout_eoff + chain + (size_t)t0s * BD;

    float h = 0.0f;
    unsigned int k0[PFP], k1[PFP];
#pragma unroll
    for (int u = 0; u < PFP; u++) {
        const uint2 v = p[(size_t)u * 64];
        k0[u] = v.x; k1[u] = v.y;
    }

    for (int t = 0; t < SEG; t += PFP) {
#pragma unroll
        for (int u = 0; u < PFP; u++) {
            const float zt = __uint_as_float(k0[u] << 16);        // tanh(z)
            const float i2 = __uint_as_float(k0[u] & 0xffff0000u);
            const float f2 = __uint_as_float(k1[u] << 16);
            const float ot = __uint_as_float(k1[u] & 0xffff0000u); // sigmoid(o)

            const uint2 nv = p[(size_t)(t + u + PFP) * 64];
            k0[u] = nv.x; k1[u] = nv.y;

            const float fm = f2 + m2;
            const float mn = fmaxf(fm, i2);
            const float ft = EXP2F(fm - mn);
            const float it = EXP2F(i2 - mn);

            c  = fmaf(ft, c, it * zt);
            n  = fmaf(ft, n, it);
            m2 = mn;
            h  = ot * c * __builtin_amdgcn_rcpf(fabsf(n) + 1e-6f);

            const size_t toff = (size_t)(t + u) * BD;
            if (MODE == 0)      hb[toff] = f2bf(h);
            else if (fl)        fo[toff] = h;
            else                bo[toff] = f2bf(h);
        }
    }

    if (seg == NSEG - 1) {
        state[0 * BD + chain] = c;
        state[1 * BD + chain] = n;
        state[2 * BD + chain] = m2;
        state[3 * BD + chain] = h;
    }
}

// ---------------------------------------------------------------------------
// Sequential sLSTM scan — general fallback (handles r != 0). When pgate=1 and
// rflag=1 the parallel path owns this layer and this kernel early-exits.
// Chainblock-tiled pre addressing (sequential per-wave stream here too).
// ---------------------------------------------------------------------------
template<int MODE>
__global__ void slstm_scan(const unsigned int* __restrict__ pre,
                           const float* __restrict__ r,
                           float* __restrict__ state,
                           unsigned short* __restrict__ hseq,
                           void* __restrict__ gout, size_t gout_eoff,
                           const int* __restrict__ flag,
                           const int* __restrict__ rflag, int T, int tpad,
                           int pgate)
{
    const int rfast = *rflag;
    if (pgate && rfast) return;

    const int idx = blockIdx.x * 64 + threadIdx.x;  // 0..BD (chain)
    const int d = idx & 1023;
    const int cb = idx >> 6, cl = idx & 63;
    const int fl = *flag;

    const float rz = r[d]            * (2.0f * L2E);
    const float ri = r[DDIM + d]     * L2E;
    const float rf = r[2 * DDIM + d] * L2E;
    const float ro = r[3 * DDIM + d] * L2E;

    float c  = state[0 * BD + idx];
    float n  = state[1 * BD + idx];
    float m2 = state[2 * BD + idx];   // log2 domain
    float h  = state[3 * BD + idx];

    const uint2* p = (const uint2*)pre + (size_t)cb * tpad * 64 + cl;

    unsigned short* hb = hseq + idx;
    float*          fo = (float*)gout + gout_eoff + idx;
    unsigned short* bo = (unsigned short*)gout + gout_eoff + idx;

    unsigned int k0[PF], k1[PF];
#pragma unroll
    for (int u = 0; u < PF; u++) {
        const uint2 v = p[(size_t)u * 64];
        k0[u] = v.x; k1[u] = v.y;
    }

    if (rfast) {
        for (int t8 = 0; t8 < T; t8 += PF) {
#pragma unroll
            for (int u = 0; u < PF; u++) {
                const float zt = __uint_as_float(k0[u] << 16);
                const float i2 = __uint_as_float(k0[u] & 0xffff0000u);
                const float f2 = __uint_as_float(k1[u] << 16);
                const float ot = __uint_as_float(k1[u] & 0xffff0000u);

                const uint2 nv = p[(size_t)(t8 + u + PF) * 64];
                k0[u] = nv.x; k1[u] = nv.y;

                const float fm = f2 + m2;
                const float mn = fmaxf(fm, i2);
                const float ft = EXP2F(fm - mn);
                const float it = EXP2F(i2 - mn);

                c  = fmaf(ft, c, it * zt);
                n  = fmaf(ft, n, it);
                m2 = mn;
                h  = ot * c * __builtin_amdgcn_rcpf(fabsf(n) + 1e-6f);

                const size_t toff = (size_t)(t8 + u) * BD;
                if (MODE == 0)      hb[toff] = f2bf(h);
                else if (fl)        fo[toff] = h;
                else                bo[toff] = f2bf(h);
            }
        }
    } else {
        for (int t8 = 0; t8 < T; t8 += PF) {
#pragma unroll
            for (int u = 0; u < PF; u++) {
                float z2 = __uint_as_float(k0[u] << 16);
                float i2 = __uint_as_float(k0[u] & 0xffff0000u);
                float f2 = __uint_as_float(k1[u] << 16);
                float o2 = __uint_as_float(k1[u] & 0xffff0000u);

                const uint2 nv = p[(size_t)(t8 + u + PF) * 64];
                k0[u] = nv.x; k1[u] = nv.y;

                z2 = fmaf(rz, h, z2);
                i2 = fmaf(ri, h, i2);
                f2 = fmaf(rf, h, f2);
                o2 = fmaf(ro, h, o2);

                const float fm = f2 + m2;
                const float mn = fmaxf(fm, i2);
                const float ft = EXP2F(fm - mn);   // <= 1
                const float it = EXP2F(i2 - mn);   // <= 1

                const float e2 = EXP2F(-fabsf(z2));
                const float zt = copysignf((1.0f - e2) * __builtin_amdgcn_rcpf(1.0f + e2), z2);
                const float ot = __builtin_amdgcn_rcpf(1.0f + EXP2F(-o2));

                c  = ft * c + it * zt;
                n  = ft * n + it;
                m2 = mn;
                h  = ot * c * __builtin_amdgcn_rcpf(fabsf(n) + 1e-6f);

                const size_t toff = (size_t)(t8 + u) * BD;
                if (MODE == 0)      hb[toff] = f2bf(h);
                else if (fl)        fo[toff] = h;
                else                bo[toff] = f2bf(h);
            }
        }
    }

    state[0 * BD + idx] = c;
    state[1 * BD + idx] = n;
    state[2 * BD + idx] = m2;
    state[3 * BD + idx] = h;
}

// ---------------------------------------------------------------------------
__global__ void finalize(const float* __restrict__ state,
                         void* __restrict__ out,
                         const int* __restrict__ flag)
{
    const int idx = blockIdx.x * 256 + threadIdx.x;  // 0..L*BD
    const int l  = idx / BD;
    const int bd = idx % BD;
    const int b = bd >> 10, d = bd & 1023;
    const float* st = state + (size_t)l * 4 * BD;
    const float cv = st[0 * BD + bd], nv = st[1 * BD + bd];
    const float mv = st[2 * BD + bd] * LN2;          // back from log2 domain
    const float hv = st[3 * BD + bd];

    const size_t hoff = (size_t)S_LEN * BD + idx;
    const size_t eoff = (size_t)S_LEN * BD + (size_t)LAYERS * BD
                      + ((size_t)l * BATCH + b) * (3 * DDIM);
    if (*flag) {
        float* o = (float*)out;
        o[hoff] = hv;
        o[eoff + d] = cv; o[eoff + DDIM + d] = nv; o[eoff + 2 * DDIM + d] = mv;
    } else {
        unsigned short* o = (unsigned short*)out;
        o[hoff] = f2bf(hv);
        o[eoff + d]            = f2bf(cv);
        o[eoff + DDIM + d]     = f2bf(nv);
        o[eoff + 2 * DDIM + d] = f2bf(mv);
    }
}

__global__ void zero_out_k(void* __restrict__ out, const int* __restrict__ flag,
                           int out_size)
{
    const size_t i = (size_t)blockIdx.x * 256 + threadIdx.x;
    const size_t nb = (size_t)out_size * ((*flag) ? 4 : 2);
    char* o = (char*)out;
    for (size_t j = i * 4; j < (i + 1) * 4 && j < nb; j++) o[j] = 0;
}

// ---------------------------------------------------------------------------
extern "C" void kernel_launch(void* const* d_in, const int* in_sizes, int n_in,
                              void* d_out, int out_size, void* d_ws, size_t ws_size,
                              hipStream_t stream)
{
    const void* input  = d_in[0];
    const void* h0     = d_in[1];
    const void* extra0 = d_in[2];
    const void* W0     = d_in[3];
    const void* b0     = d_in[4];
    const void* r0     = d_in[5];
    const void* W1     = d_in[6];
    const void* b1     = d_in[7];
    const void* r1     = d_in[8];

    const size_t FLAG_B  = 256;
    const size_t STATE_B = (size_t)LAYERS * 4 * BD * 4;   // 512 KB
    const size_t W_B     = (size_t)NG * IDIM * 2;          // 8 MB each
    const size_t PB_B    = (size_t)4 * NG * 4;             // 64 KB
    const size_t SM_B    = (size_t)4 * NSEG * BD * 4;      // 4 MB (summaries + seg-init)
    const size_t FIXED   = FLAG_B + STATE_B + 2 * W_B + PB_B + SM_B;

    int T = 0;
    for (int cand = S_LEN; cand >= 16; cand >>= 1) {   // new gemm needs T*16 % 256 == 0
        size_t need = FIXED
                    + (size_t)cand * BD * 2                   // Ain  (bf16)
                    + (size_t)cand * BD * 2                   // hseq (bf16)
                    + (size_t)(cand + PF) * BD * 8;           // pre (chainblock-tiled)
        if (need <= ws_size) { T = cand; break; }
    }

    char* ws = (char*)d_ws;
    int*   flag  = (int*)ws;
    int*   rflag = flag + 1;                               // rflag[0], rflag[1]
    float* state = (float*)(ws + FLAG_B);
    __hip_bfloat16* W0b = (__hip_bfloat16*)(ws + FLAG_B + STATE_B);
    __hip_bfloat16* W1b = W0b + (size_t)NG * IDIM;
    float* pb    = (float*)(ws + FLAG_B + STATE_B + 2 * W_B);
    float* b0f = pb, *r0f = pb + NG, *b1f = pb + 2 * NG, *r1f = pb + 3 * NG;
    float* smry  = (float*)(ws + FLAG_B + STATE_B + 2 * W_B + PB_B);
    unsigned short* Ain  = (unsigned short*)(ws + FIXED);
    unsigned short* hseq = Ain + (size_t)T * BD;
    unsigned short* pre  = hseq + (size_t)T * BD;

    detect_dtype<<<dim3(1), dim3(64), 0, stream>>>(W0, flag);

    if (T == 0) {
        zero_out_k<<<dim3((out_size + 255) / 256), dim3(256), 0, stream>>>(d_out, flag, out_size);
        return;
    }

    const int WN = NG * IDIM;
    to_bf16<<<dim3(WN / 256), dim3(256), 0, stream>>>(W0, 0, flag, (unsigned short*)W0b, WN);
    to_bf16<<<dim3(WN / 256), dim3(256), 0, stream>>>(W1, 0, flag, (unsigned short*)W1b, WN);

    prep_small<<<dim3(132), dim3(256), 0, stream>>>(h0, extra0, b0, r0, b1, r1,
                                                    flag, state, pb, rflag);

    const int  tpad = T + PF;
    const dim3 gemmGrid(DDIM / 64, (T * BATCH) / 256);   // (16, T/16)
    const dim3 scanGrid(BD / 64);
    const dim3 passGrid((BD * NSEG) / 256);
    const dim3 midGrid(BD / 256);
    const int  nch = S_LEN / T;
    // parallel path needs SEG = T/NSEG to be a positive multiple of PFP
    const int  useP = (T >= 256 && (T % (NSEG * PFP)) == 0) ? 1 : 0;

    for (int ch = 0; ch < nch; ch++) {
        const int t0 = ch * T;

        to_bf16<<<dim3((T * BD) / 256), dim3(256), 0, stream>>>(
            input, (size_t)t0 * BD, flag, Ain, T * BD);

        // ---- layer 0 ----
        gemm_bias<<<gemmGrid, 512, 0, stream>>>((const __hip_bfloat16*)Ain, W0b, b0f, pre, rflag + 0, tpad);
        if (useP) {
            scan_passA<<<passGrid, 256, 0, stream>>>((const unsigned int*)pre, rflag + 0, smry, T, tpad);
            scan_mid<<<midGrid, 256, 0, stream>>>(smry, rflag + 0, state, T);
            scan_passB<0><<<passGrid, 256, 0, stream>>>((const unsigned int*)pre, smry, rflag + 0,
                                                        state, hseq, (void*)0, 0, flag, T, tpad);
        }
        slstm_scan<0><<<scanGrid, 64, 0, stream>>>((const unsigned int*)pre, r0f, state,
                                                   hseq, (void*)0, 0, flag, rflag + 0, T, tpad, useP);

        // ---- layer 1 ----
        gemm_bias<<<gemmGrid, 512, 0, stream>>>((const __hip_bfloat16*)hseq, W1b, b1f, pre, rflag + 1, tpad);
        if (useP) {
            scan_passA<<<passGrid, 256, 0, stream>>>((const unsigned int*)pre, rflag + 1, smry, T, tpad);
            scan_mid<<<midGrid, 256, 0, stream>>>(smry, rflag + 1, state + 4 * BD, T);
            scan_passB<1><<<passGrid, 256, 0, stream>>>((const unsigned int*)pre, smry, rflag + 1,
                                                        state + 4 * BD, (unsigned short*)0,
                                                        d_out, (size_t)t0 * BD, flag, T, tpad);
        }
        slstm_scan<1><<<scanGrid, 64, 0, stream>>>((const unsigned int*)pre, r1f,
                                                   state + 4 * BD, (unsigned short*)0,
                                                   d_out, (size_t)t0 * BD, flag, rflag + 1, T, tpad, useP);
    }

    finalize<<<dim3(LAYERS * BD / 256), dim3(256), 0, stream>>>(state, d_out, flag);
}